// Round 15
// baseline (156.538 us; speedup 1.0000x reference)
//
#include <hip/hip_runtime.h>

#define BB 4
#define NN 16384
#define EE 65536
#define CC 256
#define MM 64

// ws float offsets
#define WS_NORM   0                  // B*M (atomics, memset each launch)
#define WS_T1     256
#define WS_ESN    512
#define WS_BCOMB  768                // 64
#define WS_ITX    832                // 64
#define WS_ITE    896                // 64
#define WS_WES2   1024               // 64*64 = 4096  (itE ⊙ W_eslice)
#define WS_WCOMB  5120               // C*M = 16384
#define WS_SW2    21504              // bf16 SW2 [B*N*M ushorts] lives here (8MB);
#define WS_SSUM   WS_SW2             // after kE, overlaid by Ssum [B*M*C floats]
#define WS_SPART  4215808            // B*PB*M*C partials

static __device__ __forceinline__ unsigned short f2bf(float f) {
    unsigned int u = __float_as_uint(f);
    unsigned int r = (u + 0x7FFFu + ((u >> 16) & 1u)) >> 16;   // RNE
    return (unsigned short)r;
}

// ---------- PP: merged preamble (r14 proven: -17us vs kP+kP2) ----------
__global__ __launch_bounds__(256) void kPP(const float* __restrict__ Wx,
                                           const float* __restrict__ Wsl,
                                           const float* __restrict__ bx,
                                           const float* __restrict__ phx,
                                           const float* __restrict__ bsl,
                                           const float* __restrict__ tx,
                                           const float* __restrict__ te,
                                           const float* __restrict__ Wes,
                                           float* __restrict__ ws) {
    __shared__ float row[256];
    __shared__ float part[4][64];
    const int tid = threadIdx.x;
    const int m = tid & 63, kq = tid >> 6;
    if (blockIdx.x < 256) {
        const int c = blockIdx.x;
        row[tid] = Wx[c * CC + tid];
        __syncthreads();
        float acc = 0.f;
#pragma unroll 8
        for (int kk = 0; kk < 64; ++kk) {
            int k = kq * 64 + kk;
            acc += row[k] * Wsl[k * MM + m];
        }
        part[kq][m] = acc;
        __syncthreads();
        if (tid < 64)
            ws[WS_WCOMB + c * MM + tid] =
                part[0][tid] + part[1][tid] + part[2][tid] + part[3][tid];
    } else {
        row[tid] = bx[tid] + phx[tid];
        __syncthreads();
        float acc = 0.f;
#pragma unroll 8
        for (int kk = 0; kk < 64; ++kk) {
            int k = kq * 64 + kk;
            acc += row[k] * Wsl[k * MM + m];
        }
        part[kq][m] = acc;
        __syncthreads();
        if (tid < 64) {
            ws[WS_BCOMB + tid] = bsl[tid] +
                part[0][tid] + part[1][tid] + part[2][tid] + part[3][tid];
            ws[WS_ITX + tid] = 1.f / fminf(fmaxf(tx[tid], 0.01f), 5.f);
            ws[WS_ITE + tid] = 1.f / fminf(fmaxf(te[tid], 0.01f), 5.f);
        }
#pragma unroll
        for (int i = 0; i < 16; ++i) {
            int e = i * 256 + tid;
            int k = e >> 6;
            float itk = 1.f / fminf(fmaxf(te[k], 0.01f), 5.f);
            ws[WS_WES2 + e] = itk * Wes[e];
        }
    }
}

// ---------- N1: x@W_comb -> softmax -> sw (out1) + norm + fused sw@Wes2 -> sw2b ----------
// r12 structure (68.6us proven). r15: launch_bounds 2->3 — LDS 52.7KB x3 = 158KB
// fits 160KB/CU; a 3rd independent block per CU covers the stage-barrier stall
// (r10's small-block attempt failed because it doubled staging; this keeps block
// shape identical). VGPR 88 << 170 cap at 3 waves/SIMD — no spill risk.
__global__ __launch_bounds__(256, 3) void kN1(const float* __restrict__ x,
                                              const float* __restrict__ ws,
                                              float* __restrict__ out1,
                                              unsigned short* __restrict__ sw2b,
                                              float* __restrict__ norm_acc) {
    // union: main phase: xs = smem[0..4607] (128x36), Wst = smem[4608..6655] (32x64)
    //        epilogue:  Wes2 = smem[0..4095] (64x64), swl = smem[4096..12799] (128x68)
    __shared__ float smem[12800];    // 51.2 KB
    __shared__ float redn[4][64];
    __shared__ float bcs[64], itxs[64];
    float* xs  = smem;
    float* Wst = smem + 4608;
    float* We2 = smem;
    float* swl = smem + 4096;
    const int tid = threadIdx.x;
    const int row0 = blockIdx.x * 128;
    const int b = blockIdx.x >> 7;   // 128 blocks per batch
    const int r = tid >> 2;          // 0..63 (rows r and r+64)
    const int h = tid & 3;           // m-quarter
    const float* Wc = ws + WS_WCOMB;

    if (tid < 64) { bcs[tid] = ws[WS_BCOMB + tid]; itxs[tid] = ws[WS_ITX + tid]; }

    float acc[2][16];
#pragma unroll
    for (int i = 0; i < 2; ++i)
#pragma unroll
        for (int j = 0; j < 16; ++j) acc[i][j] = 0.f;

    for (int c0 = 0; c0 < CC; c0 += 32) {
        __syncthreads();
#pragma unroll
        for (int i = 0; i < 4; ++i) {
            int flat = i * 256 + tid, rr = flat >> 3, cb = (flat & 7) * 4;
            float4 v = *(const float4*)(x + (size_t)(row0 + rr) * CC + c0 + cb);
            *(float4*)&xs[rr * 36 + cb] = v;
        }
#pragma unroll
        for (int i = 0; i < 2; ++i) {
            int f4 = i * 256 + tid;
            *(float4*)&Wst[f4 * 4] = *(const float4*)(Wc + c0 * MM + f4 * 4);
        }
        __syncthreads();
#pragma unroll
        for (int cc4 = 0; cc4 < 8; ++cc4) {
            float4 a0 = *(float4*)&xs[(r     ) * 36 + cc4 * 4];
            float4 a1 = *(float4*)&xs[(r + 64) * 36 + cc4 * 4];
            float av0[4] = {a0.x, a0.y, a0.z, a0.w};
            float av1[4] = {a1.x, a1.y, a1.z, a1.w};
#pragma unroll
            for (int k = 0; k < 4; ++k) {
                float xv0 = av0[k], xv1 = av1[k];
                const float4* wrow = (const float4*)&Wst[(cc4 * 4 + k) * 64 + h * 16];
#pragma unroll
                for (int q = 0; q < 4; ++q) {
                    float4 w = wrow[q];
                    acc[0][q * 4 + 0] += xv0 * w.x; acc[0][q * 4 + 1] += xv0 * w.y;
                    acc[0][q * 4 + 2] += xv0 * w.z; acc[0][q * 4 + 3] += xv0 * w.w;
                    acc[1][q * 4 + 0] += xv1 * w.x; acc[1][q * 4 + 1] += xv1 * w.y;
                    acc[1][q * 4 + 2] += xv1 * w.z; acc[1][q * 4 + 3] += xv1 * w.w;
                }
            }
        }
    }

    // main-phase smem dead -> stage Wes2 into smem[0..4095]
    __syncthreads();
#pragma unroll
    for (int i = 0; i < 4; ++i) {
        int f4 = i * 256 + tid;
        *(float4*)&We2[f4 * 4] = *(const float4*)(ws + WS_WES2 + f4 * 4);
    }

    // softmax per row (quad h=0..3 shares each row); write sw to out1 AND swl
    float colsum[16];
#pragma unroll
    for (int j = 0; j < 16; ++j) colsum[j] = 0.f;
#pragma unroll
    for (int i = 0; i < 2; ++i) {
        float mx = -1e30f;
#pragma unroll
        for (int j = 0; j < 16; ++j) {
            int m = h * 16 + j;
            acc[i][j] = (acc[i][j] + bcs[m]) * itxs[m];
            mx = fmaxf(mx, acc[i][j]);
        }
        mx = fmaxf(mx, __shfl_xor(mx, 1));
        mx = fmaxf(mx, __shfl_xor(mx, 2));
        float s = 0.f;
#pragma unroll
        for (int j = 0; j < 16; ++j) { acc[i][j] = __expf(acc[i][j] - mx); s += acc[i][j]; }
        s += __shfl_xor(s, 1);
        s += __shfl_xor(s, 2);
        float inv = 1.f / s;
        int rl = r + 64 * i;                 // local row 0..127
        int row = row0 + rl;
#pragma unroll
        for (int q = 0; q < 4; ++q) {
            float4 v = {acc[i][q * 4 + 0] * inv, acc[i][q * 4 + 1] * inv,
                        acc[i][q * 4 + 2] * inv, acc[i][q * 4 + 3] * inv};
            *(float4*)(out1 + (size_t)row * MM + h * 16 + q * 4) = v;
            *(float4*)&swl[rl * 68 + h * 16 + q * 4] = v;
#pragma unroll
            for (int j = 0; j < 4; ++j) colsum[q * 4 + j] += ((float*)&v)[j];
        }
    }
    // reduce colsum across the 16 r-lanes of each wave
#pragma unroll
    for (int j = 0; j < 16; ++j) {
        colsum[j] += __shfl_xor(colsum[j], 4);
        colsum[j] += __shfl_xor(colsum[j], 8);
        colsum[j] += __shfl_xor(colsum[j], 16);
        colsum[j] += __shfl_xor(colsum[j], 32);
    }
    int w = tid >> 6;
    if ((tid & 63) < 4) {
#pragma unroll
        for (int j = 0; j < 16; ++j) redn[w][h * 16 + j] = colsum[j];
    }

    // ---- fused es = sw @ Wes2, all operands from LDS (no shfl) ----
    __syncthreads();   // Wes2 + swl staged, redn written
    float es0[16], es1[16];
#pragma unroll
    for (int j = 0; j < 16; ++j) { es0[j] = 0.f; es1[j] = 0.f; }
#pragma unroll 8
    for (int k = 0; k < 64; ++k) {
        float a0 = swl[(r     ) * 68 + k];
        float a1 = swl[(r + 64) * 68 + k];
        const float4* wrow = (const float4*)&We2[k * 64 + h * 16];
#pragma unroll
        for (int j = 0; j < 4; ++j) {
            float4 wv = wrow[j];
            es0[j * 4 + 0] += a0 * wv.x; es0[j * 4 + 1] += a0 * wv.y;
            es0[j * 4 + 2] += a0 * wv.z; es0[j * 4 + 3] += a0 * wv.w;
            es1[j * 4 + 0] += a1 * wv.x; es1[j * 4 + 1] += a1 * wv.y;
            es1[j * 4 + 2] += a1 * wv.z; es1[j * 4 + 3] += a1 * wv.w;
        }
    }
    {
        size_t rowA = (size_t)(row0 + r) * MM + h * 16;
        size_t rowB = (size_t)(row0 + r + 64) * MM + h * 16;
        uint4 o;
        o.x = (unsigned int)f2bf(es0[0]) | ((unsigned int)f2bf(es0[1]) << 16);
        o.y = (unsigned int)f2bf(es0[2]) | ((unsigned int)f2bf(es0[3]) << 16);
        o.z = (unsigned int)f2bf(es0[4]) | ((unsigned int)f2bf(es0[5]) << 16);
        o.w = (unsigned int)f2bf(es0[6]) | ((unsigned int)f2bf(es0[7]) << 16);
        *(uint4*)(sw2b + rowA) = o;
        o.x = (unsigned int)f2bf(es0[8])  | ((unsigned int)f2bf(es0[9])  << 16);
        o.y = (unsigned int)f2bf(es0[10]) | ((unsigned int)f2bf(es0[11]) << 16);
        o.z = (unsigned int)f2bf(es0[12]) | ((unsigned int)f2bf(es0[13]) << 16);
        o.w = (unsigned int)f2bf(es0[14]) | ((unsigned int)f2bf(es0[15]) << 16);
        *(uint4*)(sw2b + rowA + 8) = o;
        o.x = (unsigned int)f2bf(es1[0]) | ((unsigned int)f2bf(es1[1]) << 16);
        o.y = (unsigned int)f2bf(es1[2]) | ((unsigned int)f2bf(es1[3]) << 16);
        o.z = (unsigned int)f2bf(es1[4]) | ((unsigned int)f2bf(es1[5]) << 16);
        o.w = (unsigned int)f2bf(es1[6]) | ((unsigned int)f2bf(es1[7]) << 16);
        *(uint4*)(sw2b + rowB) = o;
        o.x = (unsigned int)f2bf(es1[8])  | ((unsigned int)f2bf(es1[9])  << 16);
        o.y = (unsigned int)f2bf(es1[10]) | ((unsigned int)f2bf(es1[11]) << 16);
        o.z = (unsigned int)f2bf(es1[12]) | ((unsigned int)f2bf(es1[13]) << 16);
        o.w = (unsigned int)f2bf(es1[14]) | ((unsigned int)f2bf(es1[15]) << 16);
        *(uint4*)(sw2b + rowB + 8) = o;
    }

    if (tid < 64)
        atomicAdd(&norm_acc[b * MM + tid],
                  redn[0][tid] + redn[1][tid] + redn[2][tid] + redn[3][tid]);
}

// ---------- N2: Spart = sw_chunk^T @ x_chunk, C-split (r6 form; r15: 3 blocks/CU) ----------
__global__ __launch_bounds__(256, 3) void kN2(const float* __restrict__ x,
                                              const float* __restrict__ sw,
                                              float* __restrict__ Spart,
                                              int PB, int rowsPB) {
    __shared__ float xs[32][144];   // 18 KB, col j at j + (j>>5)*4 (2-way = free)
    __shared__ float sws[32][64];   // 8 KB
    const int bid = blockIdx.x;
    const int ch = bid & 1;
    const int p = (bid >> 1) % PB, b = (bid >> 1) / PB;
    const int base = b * NN + p * rowsPB;
    const int tid = threadIdx.x;
    const int tm = tid >> 4, tc = tid & 15;
    const int m0 = tm * 4;
    const int c0 = tc * 8;          // local col within the 128-wide half

    float acc[4][8];
#pragma unroll
    for (int mi = 0; mi < 4; ++mi)
#pragma unroll
        for (int j = 0; j < 8; ++j) acc[mi][j] = 0.f;

    for (int r0 = 0; r0 < rowsPB; r0 += 32) {
        __syncthreads();
#pragma unroll
        for (int i = 0; i < 4; ++i) {
            int flat = i * 256 + tid;
            int r = flat >> 5, c = (flat & 31) * 4;
            float4 v = *(const float4*)(x + (size_t)(base + r0 + r) * CC + ch * 128 + c);
            *(float4*)&xs[r][c + ((c >> 5) << 2)] = v;
        }
#pragma unroll
        for (int i = 0; i < 2; ++i) {
            int flat = i * 256 + tid;
            int r = flat >> 4, c = (flat & 15) * 4;
            *(float4*)&sws[r][c] = *(const float4*)(sw + (size_t)(base + r0 + r) * MM + c);
        }
        __syncthreads();
#pragma unroll 2
        for (int r = 0; r < 32; ++r) {
            float4 s4 = *(float4*)&sws[r][m0];
#pragma unroll
            for (int q = 0; q < 2; ++q) {
                int c = c0 + q * 4;
                float4 xv = *(float4*)&xs[r][c + ((c >> 5) << 2)];
                acc[0][q * 4 + 0] += s4.x * xv.x; acc[0][q * 4 + 1] += s4.x * xv.y;
                acc[0][q * 4 + 2] += s4.x * xv.z; acc[0][q * 4 + 3] += s4.x * xv.w;
                acc[1][q * 4 + 0] += s4.y * xv.x; acc[1][q * 4 + 1] += s4.y * xv.y;
                acc[1][q * 4 + 2] += s4.y * xv.z; acc[1][q * 4 + 3] += s4.y * xv.w;
                acc[2][q * 4 + 0] += s4.z * xv.x; acc[2][q * 4 + 1] += s4.z * xv.y;
                acc[2][q * 4 + 2] += s4.z * xv.z; acc[2][q * 4 + 3] += s4.z * xv.w;
                acc[3][q * 4 + 0] += s4.w * xv.x; acc[3][q * 4 + 1] += s4.w * xv.y;
                acc[3][q * 4 + 2] += s4.w * xv.z; acc[3][q * 4 + 3] += s4.w * xv.w;
            }
        }
    }
    float* dst = Spart + (size_t)(b * PB + p) * MM * CC + ch * 128;
#pragma unroll
    for (int mi = 0; mi < 4; ++mi)
#pragma unroll
        for (int q = 0; q < 2; ++q) {
            float4 v = {acc[mi][q * 4 + 0], acc[mi][q * 4 + 1],
                        acc[mi][q * 4 + 2], acc[mi][q * 4 + 3]};
            *(float4*)(dst + (size_t)(m0 + mi) * CC + c0 + q * 4) = v;
        }
}

// ---------- E: edge path (r7 form; r15: residency hint 4->8 blocks/CU) ----------
__global__ __launch_bounds__(128, 8) void kE(const float* __restrict__ eattr,
                                             const int* __restrict__ eidx,
                                             const unsigned short* __restrict__ sw2b,
                                             const float* __restrict__ bes,
                                             float* __restrict__ t1_acc,
                                             float* __restrict__ esn_acc) {
    __shared__ float u[2][64][33];
    __shared__ float eav[2][64];
    __shared__ float redt[2][64], redn[2][64];
    __shared__ float bes_s[64];
    const int tid = threadIdx.x, w = tid >> 6, l = tid & 63;
    const int eg = blockIdx.x * 128 + tid;   // 262144 edges
    const int b = eg >> 16;
    if (tid < 64) bes_s[tid] = bes[tid];
    const int2 idx = ((const int2*)eidx)[eg];
    const float ea = eattr[eg];
    const uint4* g0 = (const uint4*)(sw2b + (size_t)(b * NN + idx.x) * MM);
    const uint4* g1 = (const uint4*)(sw2b + (size_t)(b * NN + idx.y) * MM);
    eav[w][l] = ea;
    __syncthreads();

    float v[64];
#pragma unroll
    for (int q = 0; q < 8; ++q) {
        uint4 a = g0[q], c = g1[q];
        unsigned int au[4] = {a.x, a.y, a.z, a.w};
        unsigned int cu[4] = {c.x, c.y, c.z, c.w};
#pragma unroll
        for (int j = 0; j < 4; ++j) {
            int m = q * 8 + j * 2;
            v[m + 0] = __uint_as_float(au[j] << 16) + __uint_as_float(cu[j] << 16) + bes_s[m + 0];
            v[m + 1] = __uint_as_float(au[j] & 0xFFFF0000u) + __uint_as_float(cu[j] & 0xFFFF0000u) + bes_s[m + 1];
        }
    }
    float mx = -1e30f;
#pragma unroll
    for (int m = 0; m < 64; ++m) mx = fmaxf(mx, v[m]);
    float s = 0.f;
#pragma unroll
    for (int m = 0; m < 64; ++m) { v[m] = __expf(v[m] - mx); s += v[m]; }
    float inv = 1.f / s;

    const int ml = l & 31, rh = l >> 5;
#pragma unroll
    for (int ph = 0; ph < 2; ++ph) {
        __syncthreads();   // previous phase reads done before overwrite
#pragma unroll
        for (int j = 0; j < 32; ++j) u[w][l][j] = v[ph * 32 + j] * inv;
        __syncthreads();
        float t = 0.f, n = 0.f;
#pragma unroll 8
        for (int rr = 0; rr < 32; ++rr) {
            int r = rh * 32 + rr;
            float e = u[w][r][ml];
            n += e;
            t += e * eav[w][r];
        }
        t += __shfl_xor(t, 32);
        n += __shfl_xor(n, 32);
        if (l < 32) { redt[w][ph * 32 + l] = t; redn[w][ph * 32 + l] = n; }
    }
    __syncthreads();
    if (tid < 64) {
        atomicAdd(&t1_acc[b * 64 + tid], redt[0][tid] + redt[1][tid]);
        atomicAdd(&esn_acc[b * 64 + tid], redn[0][tid] + redn[1][tid]);
    }
}

// ---------- R: parallel partial reduce Spart -> Ssum [B,M,C] ----------
__global__ __launch_bounds__(256) void kR(const float* __restrict__ Spart,
                                          float* __restrict__ Ssum, int PB) {
    const int idx = blockIdx.x * 256 + threadIdx.x;  // B*M*C = 262144
    const int b = idx >> 14;                          // M*C = 16384 per b
    const int mc = idx & 16383;
    const float* sp = Spart + (size_t)b * PB * MM * CC + mc;
    float a0 = 0.f, a1 = 0.f, a2 = 0.f, a3 = 0.f;
    for (int p = 0; p < PB; p += 4) {
        a0 += sp[(size_t)(p + 0) * MM * CC];
        a1 += sp[(size_t)(p + 1) * MM * CC];
        a2 += sp[(size_t)(p + 2) * MM * CC];
        a3 += sp[(size_t)(p + 3) * MM * CC];
    }
    Ssum[idx] = (a0 + a1) + (a2 + a3);
}

// ---------- F2: matvec + combine -> slice_token ----------
__global__ __launch_bounds__(256) void kF2(const float* __restrict__ ws,
                                           const float* __restrict__ Wfx,
                                           const float* __restrict__ bfx,
                                           const float* __restrict__ Wfe,
                                           const float* __restrict__ bfe,
                                           const float* __restrict__ phe,
                                           float* __restrict__ out0) {
    __shared__ float srow[256];
    const int bid = blockIdx.x;          // 256 blocks = (b,m)
    const int b = bid >> 6, m = bid & 63;
    const int t = threadIdx.x;
    srow[t] = ws[WS_SSUM + (size_t)(b * MM + m) * CC + t];
    __syncthreads();
    float acc = 0.f;
#pragma unroll 8
    for (int k = 0; k < 256; ++k) acc += srow[k] * Wfx[k * CC + t];
    float nv  = ws[WS_NORM + b * 64 + m];
    float t1v = ws[WS_T1   + b * 64 + m];
    float ev  = ws[WS_ESN  + b * 64 + m];
    const float scale = (float)NN / (float)EE;   // 0.25
    float num = acc + nv * bfx[t] + scale * (t1v * Wfe[t] + ev * (bfe[t] + phe[t]));
    float den = nv + scale * ev + 1e-5f;
    out0[(size_t)(b * MM + m) * CC + t] = num / den;
}

extern "C" void kernel_launch(void* const* d_in, const int* in_sizes, int n_in,
                              void* d_out, int out_size, void* d_ws, size_t ws_size,
                              hipStream_t stream) {
    const float* x     = (const float*)d_in[0];
    const float* eattr = (const float*)d_in[1];
    const int*   eidx  = (const int*)d_in[2];
    const float* Wfx   = (const float*)d_in[3];
    const float* bfx   = (const float*)d_in[4];
    const float* Wx    = (const float*)d_in[5];
    const float* bx    = (const float*)d_in[6];
    const float* Wsl   = (const float*)d_in[7];
    const float* bsl   = (const float*)d_in[8];
    const float* tx    = (const float*)d_in[9];
    const float* phx   = (const float*)d_in[10];
    const float* Wfe   = (const float*)d_in[11];
    const float* bfe   = (const float*)d_in[12];
    const float* te    = (const float*)d_in[13];
    const float* Wes   = (const float*)d_in[14];
    const float* bes   = (const float*)d_in[15];
    const float* phe   = (const float*)d_in[16];

    float* out0 = (float*)d_out;                  // slice_token [B,M,C]
    float* out1 = out0 + (size_t)BB * MM * CC;    // slice_weight [B,N,M]
    float* ws   = (float*)d_ws;
    unsigned short* sw2b = (unsigned short*)(ws + WS_SW2);

    int PB = 64;
    while (PB > 8) {
        size_t need = (size_t)(WS_SPART + (size_t)BB * PB * MM * CC) * sizeof(float);
        if (need <= ws_size) break;
        PB >>= 1;
    }
    int rowsPB = NN / PB;

    hipMemsetAsync(ws, 0, 768 * sizeof(float), stream);

    kPP<<<257, 256, 0, stream>>>(Wx, Wsl, bx, phx, bsl, tx, te, Wes, ws);
    kN1<<<512, 256, 0, stream>>>(x, ws, out1, sw2b, ws + WS_NORM);
    kE <<<2048, 128, 0, stream>>>(eattr, eidx, sw2b, bes,
                                  ws + WS_T1, ws + WS_ESN);
    kN2<<<BB * PB * 2, 256, 0, stream>>>(x, out1, ws + WS_SPART, PB, rowsPB);
    kR <<<1024, 256, 0, stream>>>(ws + WS_SPART, ws + WS_SSUM, PB);
    kF2<<<256, 256, 0, stream>>>(ws, Wfx, bfx, Wfe, bfe, phe, out0);
}

// Round 16
// 154.956 us; speedup vs baseline: 1.0102x; 1.0102x over previous
//
#include <hip/hip_runtime.h>

#define BB 4
#define NN 16384
#define EE 65536
#define CC 256
#define MM 64

// ws float offsets
#define WS_NORM   0                  // B*M (atomics, memset each launch)
#define WS_T1     256
#define WS_ESN    512
#define WS_BCOMB  768                // 64
#define WS_ITX    832                // 64
#define WS_ITE    896                // 64
#define WS_WES2   1024               // 64*64 = 4096  (itE ⊙ W_eslice)
#define WS_WCOMB  5120               // C*M = 16384
#define WS_SW2    21504              // bf16 SW2 [B*N*M ushorts] lives here (8MB);
#define WS_SSUM   WS_SW2             // after kE, overlaid by Ssum [B*M*C floats]
#define WS_SPART  4215808            // B*PB*M*C partials

static __device__ __forceinline__ unsigned short f2bf(float f) {
    unsigned int u = __float_as_uint(f);
    unsigned int r = (u + 0x7FFFu + ((u >> 16) & 1u)) >> 16;   // RNE
    return (unsigned short)r;
}

// ---------- PP: merged preamble (r14 proven: -17us vs kP+kP2) ----------
__global__ __launch_bounds__(256) void kPP(const float* __restrict__ Wx,
                                           const float* __restrict__ Wsl,
                                           const float* __restrict__ bx,
                                           const float* __restrict__ phx,
                                           const float* __restrict__ bsl,
                                           const float* __restrict__ tx,
                                           const float* __restrict__ te,
                                           const float* __restrict__ Wes,
                                           float* __restrict__ ws) {
    __shared__ float row[256];
    __shared__ float part[4][64];
    const int tid = threadIdx.x;
    const int m = tid & 63, kq = tid >> 6;
    if (blockIdx.x < 256) {
        const int c = blockIdx.x;
        row[tid] = Wx[c * CC + tid];
        __syncthreads();
        float acc = 0.f;
#pragma unroll 8
        for (int kk = 0; kk < 64; ++kk) {
            int k = kq * 64 + kk;
            acc += row[k] * Wsl[k * MM + m];
        }
        part[kq][m] = acc;
        __syncthreads();
        if (tid < 64)
            ws[WS_WCOMB + c * MM + tid] =
                part[0][tid] + part[1][tid] + part[2][tid] + part[3][tid];
    } else {
        row[tid] = bx[tid] + phx[tid];
        __syncthreads();
        float acc = 0.f;
#pragma unroll 8
        for (int kk = 0; kk < 64; ++kk) {
            int k = kq * 64 + kk;
            acc += row[k] * Wsl[k * MM + m];
        }
        part[kq][m] = acc;
        __syncthreads();
        if (tid < 64) {
            ws[WS_BCOMB + tid] = bsl[tid] +
                part[0][tid] + part[1][tid] + part[2][tid] + part[3][tid];
            ws[WS_ITX + tid] = 1.f / fminf(fmaxf(tx[tid], 0.01f), 5.f);
            ws[WS_ITE + tid] = 1.f / fminf(fmaxf(te[tid], 0.01f), 5.f);
        }
#pragma unroll
        for (int i = 0; i < 16; ++i) {
            int e = i * 256 + tid;
            int k = e >> 6;
            float itk = 1.f / fminf(fmaxf(te[k], 0.01f), 5.f);
            ws[WS_WES2 + e] = itk * Wes[e];
        }
    }
}

// ---------- N1: x@W_comb -> softmax -> sw (out1) + norm + fused sw@Wes2 -> sw2b ----------
// r16: LDS-issue-bound diagnosis (r15 model: 7.1 FMA per ds_read_b128). Deeper
// register blocking: thread owns 4 rows x 16 m (acc[4][16]); 256 rows/block,
// grid 256 (1 block/CU, 4 waves). Each W-b128 now feeds 16 FMA (ratio 12.8).
// LDS union 86KB (>64KB OK on gfx950). Epilogue = r12 LDS-roundtrip, 4 rows.
__global__ __launch_bounds__(256, 1) void kN1(const float* __restrict__ x,
                                              const float* __restrict__ ws,
                                              float* __restrict__ out1,
                                              unsigned short* __restrict__ sw2b,
                                              float* __restrict__ norm_acc) {
    // main: xs = smem[0..9215] (256x36), Wst = smem[9216..11263] (32x64)
    // epi:  We2 = smem[0..4095] (64x64), swl = smem[4096..21503] (256x68)
    __shared__ float smem[21504];    // 86 KB
    __shared__ float redn[4][64];
    __shared__ float bcs[64], itxs[64];
    float* xs  = smem;
    float* Wst = smem + 9216;
    float* We2 = smem;
    float* swl = smem + 4096;
    const int tid = threadIdx.x;
    const int row0 = blockIdx.x * 256;
    const int b = blockIdx.x >> 6;   // 64 blocks per batch
    const int r = tid >> 2;          // 0..63; rows r+64*i, i=0..3
    const int h = tid & 3;           // m-quarter
    const float* Wc = ws + WS_WCOMB;

    if (tid < 64) { bcs[tid] = ws[WS_BCOMB + tid]; itxs[tid] = ws[WS_ITX + tid]; }

    float acc[4][16];
#pragma unroll
    for (int i = 0; i < 4; ++i)
#pragma unroll
        for (int j = 0; j < 16; ++j) acc[i][j] = 0.f;

    for (int c0 = 0; c0 < CC; c0 += 32) {
        __syncthreads();
        // stage x[row0..row0+255][c0..c0+31]: 2048 float4, 8 per thread
#pragma unroll
        for (int i = 0; i < 8; ++i) {
            int flat = i * 256 + tid, rr = flat >> 3, cb = (flat & 7) * 4;
            float4 v = *(const float4*)(x + (size_t)(row0 + rr) * CC + c0 + cb);
            *(float4*)&xs[rr * 36 + cb] = v;
        }
#pragma unroll
        for (int i = 0; i < 2; ++i) {
            int f4 = i * 256 + tid;
            *(float4*)&Wst[f4 * 4] = *(const float4*)(Wc + c0 * MM + f4 * 4);
        }
        __syncthreads();
#pragma unroll
        for (int cc4 = 0; cc4 < 8; ++cc4) {
            float4 a0 = *(float4*)&xs[(r      ) * 36 + cc4 * 4];
            float4 a1 = *(float4*)&xs[(r +  64) * 36 + cc4 * 4];
            float4 a2 = *(float4*)&xs[(r + 128) * 36 + cc4 * 4];
            float4 a3 = *(float4*)&xs[(r + 192) * 36 + cc4 * 4];
            float av0[4] = {a0.x, a0.y, a0.z, a0.w};
            float av1[4] = {a1.x, a1.y, a1.z, a1.w};
            float av2[4] = {a2.x, a2.y, a2.z, a2.w};
            float av3[4] = {a3.x, a3.y, a3.z, a3.w};
#pragma unroll
            for (int k = 0; k < 4; ++k) {
                float xv0 = av0[k], xv1 = av1[k], xv2 = av2[k], xv3 = av3[k];
                const float4* wrow = (const float4*)&Wst[(cc4 * 4 + k) * 64 + h * 16];
#pragma unroll
                for (int q = 0; q < 4; ++q) {
                    float4 w = wrow[q];
                    acc[0][q * 4 + 0] += xv0 * w.x; acc[0][q * 4 + 1] += xv0 * w.y;
                    acc[0][q * 4 + 2] += xv0 * w.z; acc[0][q * 4 + 3] += xv0 * w.w;
                    acc[1][q * 4 + 0] += xv1 * w.x; acc[1][q * 4 + 1] += xv1 * w.y;
                    acc[1][q * 4 + 2] += xv1 * w.z; acc[1][q * 4 + 3] += xv1 * w.w;
                    acc[2][q * 4 + 0] += xv2 * w.x; acc[2][q * 4 + 1] += xv2 * w.y;
                    acc[2][q * 4 + 2] += xv2 * w.z; acc[2][q * 4 + 3] += xv2 * w.w;
                    acc[3][q * 4 + 0] += xv3 * w.x; acc[3][q * 4 + 1] += xv3 * w.y;
                    acc[3][q * 4 + 2] += xv3 * w.z; acc[3][q * 4 + 3] += xv3 * w.w;
                }
            }
        }
    }

    // main-phase smem dead -> stage Wes2 into smem[0..4095]
    __syncthreads();
#pragma unroll
    for (int i = 0; i < 4; ++i) {
        int f4 = i * 256 + tid;
        *(float4*)&We2[f4 * 4] = *(const float4*)(ws + WS_WES2 + f4 * 4);
    }

    // softmax per row (quad h=0..3 shares each row); write sw to out1 AND swl
    float colsum[16];
#pragma unroll
    for (int j = 0; j < 16; ++j) colsum[j] = 0.f;
#pragma unroll
    for (int i = 0; i < 4; ++i) {
        float mx = -1e30f;
#pragma unroll
        for (int j = 0; j < 16; ++j) {
            int m = h * 16 + j;
            acc[i][j] = (acc[i][j] + bcs[m]) * itxs[m];
            mx = fmaxf(mx, acc[i][j]);
        }
        mx = fmaxf(mx, __shfl_xor(mx, 1));
        mx = fmaxf(mx, __shfl_xor(mx, 2));
        float s = 0.f;
#pragma unroll
        for (int j = 0; j < 16; ++j) { acc[i][j] = __expf(acc[i][j] - mx); s += acc[i][j]; }
        s += __shfl_xor(s, 1);
        s += __shfl_xor(s, 2);
        float inv = 1.f / s;
        int rl = r + 64 * i;                 // local row 0..255
        int row = row0 + rl;
#pragma unroll
        for (int q = 0; q < 4; ++q) {
            float4 v = {acc[i][q * 4 + 0] * inv, acc[i][q * 4 + 1] * inv,
                        acc[i][q * 4 + 2] * inv, acc[i][q * 4 + 3] * inv};
            *(float4*)(out1 + (size_t)row * MM + h * 16 + q * 4) = v;
            *(float4*)&swl[rl * 68 + h * 16 + q * 4] = v;
#pragma unroll
            for (int j = 0; j < 4; ++j) colsum[q * 4 + j] += ((float*)&v)[j];
        }
    }
    // reduce colsum across the 16 r-lanes of each wave
#pragma unroll
    for (int j = 0; j < 16; ++j) {
        colsum[j] += __shfl_xor(colsum[j], 4);
        colsum[j] += __shfl_xor(colsum[j], 8);
        colsum[j] += __shfl_xor(colsum[j], 16);
        colsum[j] += __shfl_xor(colsum[j], 32);
    }
    int w = tid >> 6;
    if ((tid & 63) < 4) {
#pragma unroll
        for (int j = 0; j < 16; ++j) redn[w][h * 16 + j] = colsum[j];
    }

    // ---- fused es = sw @ Wes2, all operands from LDS (no shfl) ----
    __syncthreads();   // Wes2 + swl staged, redn written
    float es[4][16];
#pragma unroll
    for (int i = 0; i < 4; ++i)
#pragma unroll
        for (int j = 0; j < 16; ++j) es[i][j] = 0.f;
#pragma unroll 8
    for (int k = 0; k < 64; ++k) {
        float a0 = swl[(r      ) * 68 + k];
        float a1 = swl[(r +  64) * 68 + k];
        float a2 = swl[(r + 128) * 68 + k];
        float a3 = swl[(r + 192) * 68 + k];
        const float4* wrow = (const float4*)&We2[k * 64 + h * 16];
#pragma unroll
        for (int j = 0; j < 4; ++j) {
            float4 wv = wrow[j];
            es[0][j * 4 + 0] += a0 * wv.x; es[0][j * 4 + 1] += a0 * wv.y;
            es[0][j * 4 + 2] += a0 * wv.z; es[0][j * 4 + 3] += a0 * wv.w;
            es[1][j * 4 + 0] += a1 * wv.x; es[1][j * 4 + 1] += a1 * wv.y;
            es[1][j * 4 + 2] += a1 * wv.z; es[1][j * 4 + 3] += a1 * wv.w;
            es[2][j * 4 + 0] += a2 * wv.x; es[2][j * 4 + 1] += a2 * wv.y;
            es[2][j * 4 + 2] += a2 * wv.z; es[2][j * 4 + 3] += a2 * wv.w;
            es[3][j * 4 + 0] += a3 * wv.x; es[3][j * 4 + 1] += a3 * wv.y;
            es[3][j * 4 + 2] += a3 * wv.z; es[3][j * 4 + 3] += a3 * wv.w;
        }
    }
#pragma unroll
    for (int i = 0; i < 4; ++i) {
        size_t rowA = (size_t)(row0 + r + 64 * i) * MM + h * 16;
        uint4 o;
        o.x = (unsigned int)f2bf(es[i][0]) | ((unsigned int)f2bf(es[i][1]) << 16);
        o.y = (unsigned int)f2bf(es[i][2]) | ((unsigned int)f2bf(es[i][3]) << 16);
        o.z = (unsigned int)f2bf(es[i][4]) | ((unsigned int)f2bf(es[i][5]) << 16);
        o.w = (unsigned int)f2bf(es[i][6]) | ((unsigned int)f2bf(es[i][7]) << 16);
        *(uint4*)(sw2b + rowA) = o;
        o.x = (unsigned int)f2bf(es[i][8])  | ((unsigned int)f2bf(es[i][9])  << 16);
        o.y = (unsigned int)f2bf(es[i][10]) | ((unsigned int)f2bf(es[i][11]) << 16);
        o.z = (unsigned int)f2bf(es[i][12]) | ((unsigned int)f2bf(es[i][13]) << 16);
        o.w = (unsigned int)f2bf(es[i][14]) | ((unsigned int)f2bf(es[i][15]) << 16);
        *(uint4*)(sw2b + rowA + 8) = o;
    }

    if (tid < 64)
        atomicAdd(&norm_acc[b * MM + tid],
                  redn[0][tid] + redn[1][tid] + redn[2][tid] + redn[3][tid]);
}

// ---------- N2: Spart = sw_chunk^T @ x_chunk, C-split (r6/r14 exact form) ----------
__global__ __launch_bounds__(256, 2) void kN2(const float* __restrict__ x,
                                              const float* __restrict__ sw,
                                              float* __restrict__ Spart,
                                              int PB, int rowsPB) {
    __shared__ float xs[32][144];   // 18 KB, col j at j + (j>>5)*4 (2-way = free)
    __shared__ float sws[32][64];   // 8 KB
    const int bid = blockIdx.x;
    const int ch = bid & 1;
    const int p = (bid >> 1) % PB, b = (bid >> 1) / PB;
    const int base = b * NN + p * rowsPB;
    const int tid = threadIdx.x;
    const int tm = tid >> 4, tc = tid & 15;
    const int m0 = tm * 4;
    const int c0 = tc * 8;          // local col within the 128-wide half

    float acc[4][8];
#pragma unroll
    for (int mi = 0; mi < 4; ++mi)
#pragma unroll
        for (int j = 0; j < 8; ++j) acc[mi][j] = 0.f;

    for (int r0 = 0; r0 < rowsPB; r0 += 32) {
        __syncthreads();
#pragma unroll
        for (int i = 0; i < 4; ++i) {
            int flat = i * 256 + tid;
            int r = flat >> 5, c = (flat & 31) * 4;
            float4 v = *(const float4*)(x + (size_t)(base + r0 + r) * CC + ch * 128 + c);
            *(float4*)&xs[r][c + ((c >> 5) << 2)] = v;
        }
#pragma unroll
        for (int i = 0; i < 2; ++i) {
            int flat = i * 256 + tid;
            int r = flat >> 4, c = (flat & 15) * 4;
            *(float4*)&sws[r][c] = *(const float4*)(sw + (size_t)(base + r0 + r) * MM + c);
        }
        __syncthreads();
#pragma unroll 2
        for (int r = 0; r < 32; ++r) {
            float4 s4 = *(float4*)&sws[r][m0];
#pragma unroll
            for (int q = 0; q < 2; ++q) {
                int c = c0 + q * 4;
                float4 xv = *(float4*)&xs[r][c + ((c >> 5) << 2)];
                acc[0][q * 4 + 0] += s4.x * xv.x; acc[0][q * 4 + 1] += s4.x * xv.y;
                acc[0][q * 4 + 2] += s4.x * xv.z; acc[0][q * 4 + 3] += s4.x * xv.w;
                acc[1][q * 4 + 0] += s4.y * xv.x; acc[1][q * 4 + 1] += s4.y * xv.y;
                acc[1][q * 4 + 2] += s4.y * xv.z; acc[1][q * 4 + 3] += s4.y * xv.w;
                acc[2][q * 4 + 0] += s4.z * xv.x; acc[2][q * 4 + 1] += s4.z * xv.y;
                acc[2][q * 4 + 2] += s4.z * xv.z; acc[2][q * 4 + 3] += s4.z * xv.w;
                acc[3][q * 4 + 0] += s4.w * xv.x; acc[3][q * 4 + 1] += s4.w * xv.y;
                acc[3][q * 4 + 2] += s4.w * xv.z; acc[3][q * 4 + 3] += s4.w * xv.w;
            }
        }
    }
    float* dst = Spart + (size_t)(b * PB + p) * MM * CC + ch * 128;
#pragma unroll
    for (int mi = 0; mi < 4; ++mi)
#pragma unroll
        for (int q = 0; q < 2; ++q) {
            float4 v = {acc[mi][q * 4 + 0], acc[mi][q * 4 + 1],
                        acc[mi][q * 4 + 2], acc[mi][q * 4 + 3]};
            *(float4*)(dst + (size_t)(m0 + mi) * CC + c0 + q * 4) = v;
        }
}

// ---------- E: edge path (r7/r14 exact form, hint 4) ----------
__global__ __launch_bounds__(128, 4) void kE(const float* __restrict__ eattr,
                                             const int* __restrict__ eidx,
                                             const unsigned short* __restrict__ sw2b,
                                             const float* __restrict__ bes,
                                             float* __restrict__ t1_acc,
                                             float* __restrict__ esn_acc) {
    __shared__ float u[2][64][33];
    __shared__ float eav[2][64];
    __shared__ float redt[2][64], redn[2][64];
    __shared__ float bes_s[64];
    const int tid = threadIdx.x, w = tid >> 6, l = tid & 63;
    const int eg = blockIdx.x * 128 + tid;   // 262144 edges
    const int b = eg >> 16;
    if (tid < 64) bes_s[tid] = bes[tid];
    const int2 idx = ((const int2*)eidx)[eg];
    const float ea = eattr[eg];
    const uint4* g0 = (const uint4*)(sw2b + (size_t)(b * NN + idx.x) * MM);
    const uint4* g1 = (const uint4*)(sw2b + (size_t)(b * NN + idx.y) * MM);
    eav[w][l] = ea;
    __syncthreads();

    float v[64];
#pragma unroll
    for (int q = 0; q < 8; ++q) {
        uint4 a = g0[q], c = g1[q];
        unsigned int au[4] = {a.x, a.y, a.z, a.w};
        unsigned int cu[4] = {c.x, c.y, c.z, c.w};
#pragma unroll
        for (int j = 0; j < 4; ++j) {
            int m = q * 8 + j * 2;
            v[m + 0] = __uint_as_float(au[j] << 16) + __uint_as_float(cu[j] << 16) + bes_s[m + 0];
            v[m + 1] = __uint_as_float(au[j] & 0xFFFF0000u) + __uint_as_float(cu[j] & 0xFFFF0000u) + bes_s[m + 1];
        }
    }
    float mx = -1e30f;
#pragma unroll
    for (int m = 0; m < 64; ++m) mx = fmaxf(mx, v[m]);
    float s = 0.f;
#pragma unroll
    for (int m = 0; m < 64; ++m) { v[m] = __expf(v[m] - mx); s += v[m]; }
    float inv = 1.f / s;

    const int ml = l & 31, rh = l >> 5;
#pragma unroll
    for (int ph = 0; ph < 2; ++ph) {
        __syncthreads();   // previous phase reads done before overwrite
#pragma unroll
        for (int j = 0; j < 32; ++j) u[w][l][j] = v[ph * 32 + j] * inv;
        __syncthreads();
        float t = 0.f, n = 0.f;
#pragma unroll 8
        for (int rr = 0; rr < 32; ++rr) {
            int r = rh * 32 + rr;
            float e = u[w][r][ml];
            n += e;
            t += e * eav[w][r];
        }
        t += __shfl_xor(t, 32);
        n += __shfl_xor(n, 32);
        if (l < 32) { redt[w][ph * 32 + l] = t; redn[w][ph * 32 + l] = n; }
    }
    __syncthreads();
    if (tid < 64) {
        atomicAdd(&t1_acc[b * 64 + tid], redt[0][tid] + redt[1][tid]);
        atomicAdd(&esn_acc[b * 64 + tid], redn[0][tid] + redn[1][tid]);
    }
}

// ---------- R: parallel partial reduce Spart -> Ssum [B,M,C] ----------
__global__ __launch_bounds__(256) void kR(const float* __restrict__ Spart,
                                          float* __restrict__ Ssum, int PB) {
    const int idx = blockIdx.x * 256 + threadIdx.x;  // B*M*C = 262144
    const int b = idx >> 14;                          // M*C = 16384 per b
    const int mc = idx & 16383;
    const float* sp = Spart + (size_t)b * PB * MM * CC + mc;
    float a0 = 0.f, a1 = 0.f, a2 = 0.f, a3 = 0.f;
    for (int p = 0; p < PB; p += 4) {
        a0 += sp[(size_t)(p + 0) * MM * CC];
        a1 += sp[(size_t)(p + 1) * MM * CC];
        a2 += sp[(size_t)(p + 2) * MM * CC];
        a3 += sp[(size_t)(p + 3) * MM * CC];
    }
    Ssum[idx] = (a0 + a1) + (a2 + a3);
}

// ---------- F2: matvec + combine -> slice_token ----------
__global__ __launch_bounds__(256) void kF2(const float* __restrict__ ws,
                                           const float* __restrict__ Wfx,
                                           const float* __restrict__ bfx,
                                           const float* __restrict__ Wfe,
                                           const float* __restrict__ bfe,
                                           const float* __restrict__ phe,
                                           float* __restrict__ out0) {
    __shared__ float srow[256];
    const int bid = blockIdx.x;          // 256 blocks = (b,m)
    const int b = bid >> 6, m = bid & 63;
    const int t = threadIdx.x;
    srow[t] = ws[WS_SSUM + (size_t)(b * MM + m) * CC + t];
    __syncthreads();
    float acc = 0.f;
#pragma unroll 8
    for (int k = 0; k < 256; ++k) acc += srow[k] * Wfx[k * CC + t];
    float nv  = ws[WS_NORM + b * 64 + m];
    float t1v = ws[WS_T1   + b * 64 + m];
    float ev  = ws[WS_ESN  + b * 64 + m];
    const float scale = (float)NN / (float)EE;   // 0.25
    float num = acc + nv * bfx[t] + scale * (t1v * Wfe[t] + ev * (bfe[t] + phe[t]));
    float den = nv + scale * ev + 1e-5f;
    out0[(size_t)(b * MM + m) * CC + t] = num / den;
}

extern "C" void kernel_launch(void* const* d_in, const int* in_sizes, int n_in,
                              void* d_out, int out_size, void* d_ws, size_t ws_size,
                              hipStream_t stream) {
    const float* x     = (const float*)d_in[0];
    const float* eattr = (const float*)d_in[1];
    const int*   eidx  = (const int*)d_in[2];
    const float* Wfx   = (const float*)d_in[3];
    const float* bfx   = (const float*)d_in[4];
    const float* Wx    = (const float*)d_in[5];
    const float* bx    = (const float*)d_in[6];
    const float* Wsl   = (const float*)d_in[7];
    const float* bsl   = (const float*)d_in[8];
    const float* tx    = (const float*)d_in[9];
    const float* phx   = (const float*)d_in[10];
    const float* Wfe   = (const float*)d_in[11];
    const float* bfe   = (const float*)d_in[12];
    const float* te    = (const float*)d_in[13];
    const float* Wes   = (const float*)d_in[14];
    const float* bes   = (const float*)d_in[15];
    const float* phe   = (const float*)d_in[16];

    float* out0 = (float*)d_out;                  // slice_token [B,M,C]
    float* out1 = out0 + (size_t)BB * MM * CC;    // slice_weight [B,N,M]
    float* ws   = (float*)d_ws;
    unsigned short* sw2b = (unsigned short*)(ws + WS_SW2);

    int PB = 64;
    while (PB > 8) {
        size_t need = (size_t)(WS_SPART + (size_t)BB * PB * MM * CC) * sizeof(float);
        if (need <= ws_size) break;
        PB >>= 1;
    }
    int rowsPB = NN / PB;

    hipMemsetAsync(ws, 0, 768 * sizeof(float), stream);

    kPP<<<257, 256, 0, stream>>>(Wx, Wsl, bx, phx, bsl, tx, te, Wes, ws);
    kN1<<<256, 256, 0, stream>>>(x, ws, out1, sw2b, ws + WS_NORM);
    kE <<<2048, 128, 0, stream>>>(eattr, eidx, sw2b, bes,
                                  ws + WS_T1, ws + WS_ESN);
    kN2<<<BB * PB * 2, 256, 0, stream>>>(x, out1, ws + WS_SPART, PB, rowsPB);
    kR <<<1024, 256, 0, stream>>>(ws + WS_SPART, ws + WS_SSUM, PB);
    kF2<<<256, 256, 0, stream>>>(ws, Wfx, bfx, Wfe, bfe, phe, out0);
}

// Round 17
// 128.098 us; speedup vs baseline: 1.2220x; 1.2097x over previous
//
#include <hip/hip_runtime.h>

#define BB 4
#define NN 16384
#define EE 65536
#define CC 256
#define MM 64

// ws float offsets
#define WS_NORM   0                  // B*M (atomics, zeroed by kPP block 256)
#define WS_T1     256
#define WS_ESN    512
#define WS_BCOMB  768                // 64
#define WS_ITX    832                // 64
#define WS_ITE    896                // 64
#define WS_WES2   1024               // 64*64 = 4096  (itE ⊙ W_eslice)
#define WS_WCOMB  5120               // C*M = 16384
#define WS_SW2    21504              // bf16 SW2 [B*N*M ushorts] lives here (8MB);
#define WS_SSUM   WS_SW2             // after kEN2, overlaid by Ssum [B*M*C floats]
#define WS_SPART  4215808            // B*PB*M*C partials

static __device__ __forceinline__ unsigned short f2bf(float f) {
    unsigned int u = __float_as_uint(f);
    unsigned int r = (u + 0x7FFFu + ((u >> 16) & 1u)) >> 16;   // RNE
    return (unsigned short)r;
}

// ---------- PP: merged preamble + accumulator zeroing ----------
__global__ __launch_bounds__(256) void kPP(const float* __restrict__ Wx,
                                           const float* __restrict__ Wsl,
                                           const float* __restrict__ bx,
                                           const float* __restrict__ phx,
                                           const float* __restrict__ bsl,
                                           const float* __restrict__ tx,
                                           const float* __restrict__ te,
                                           const float* __restrict__ Wes,
                                           float* __restrict__ ws) {
    __shared__ float row[256];
    __shared__ float part[4][64];
    const int tid = threadIdx.x;
    const int m = tid & 63, kq = tid >> 6;
    if (blockIdx.x < 256) {
        const int c = blockIdx.x;
        row[tid] = Wx[c * CC + tid];
        __syncthreads();
        float acc = 0.f;
#pragma unroll 8
        for (int kk = 0; kk < 64; ++kk) {
            int k = kq * 64 + kk;
            acc += row[k] * Wsl[k * MM + m];
        }
        part[kq][m] = acc;
        __syncthreads();
        if (tid < 64)
            ws[WS_WCOMB + c * MM + tid] =
                part[0][tid] + part[1][tid] + part[2][tid] + part[3][tid];
    } else {
        // zero atomic accumulators (replaces hipMemsetAsync)
#pragma unroll
        for (int i = 0; i < 3; ++i) ws[i * 256 + tid] = 0.f;
        row[tid] = bx[tid] + phx[tid];
        __syncthreads();
        float acc = 0.f;
#pragma unroll 8
        for (int kk = 0; kk < 64; ++kk) {
            int k = kq * 64 + kk;
            acc += row[k] * Wsl[k * MM + m];
        }
        part[kq][m] = acc;
        __syncthreads();
        if (tid < 64) {
            ws[WS_BCOMB + tid] = bsl[tid] +
                part[0][tid] + part[1][tid] + part[2][tid] + part[3][tid];
            ws[WS_ITX + tid] = 1.f / fminf(fmaxf(tx[tid], 0.01f), 5.f);
            ws[WS_ITE + tid] = 1.f / fminf(fmaxf(te[tid], 0.01f), 5.f);
        }
#pragma unroll
        for (int i = 0; i < 16; ++i) {
            int e = i * 256 + tid;
            int k = e >> 6;
            float itk = 1.f / fminf(fmaxf(te[k], 0.01f), 5.f);
            ws[WS_WES2 + e] = itk * Wes[e];
        }
    }
}

// ---------- N1: EXACT r12 form (68us proven; r16's 4-row tile spilled -> 97us) ----------
__global__ __launch_bounds__(256, 2) void kN1(const float* __restrict__ x,
                                              const float* __restrict__ ws,
                                              float* __restrict__ out1,
                                              unsigned short* __restrict__ sw2b,
                                              float* __restrict__ norm_acc) {
    // union: main phase: xs = smem[0..4607] (128x36), Wst = smem[4608..6655] (32x64)
    //        epilogue:  Wes2 = smem[0..4095] (64x64), swl = smem[4096..12799] (128x68)
    __shared__ float smem[12800];    // 51.2 KB
    __shared__ float redn[4][64];
    __shared__ float bcs[64], itxs[64];
    float* xs  = smem;
    float* Wst = smem + 4608;
    float* We2 = smem;
    float* swl = smem + 4096;
    const int tid = threadIdx.x;
    const int row0 = blockIdx.x * 128;
    const int b = blockIdx.x >> 7;   // 128 blocks per batch
    const int r = tid >> 2;          // 0..63 (rows r and r+64)
    const int h = tid & 3;           // m-quarter
    const float* Wc = ws + WS_WCOMB;

    if (tid < 64) { bcs[tid] = ws[WS_BCOMB + tid]; itxs[tid] = ws[WS_ITX + tid]; }

    float acc[2][16];
#pragma unroll
    for (int i = 0; i < 2; ++i)
#pragma unroll
        for (int j = 0; j < 16; ++j) acc[i][j] = 0.f;

    for (int c0 = 0; c0 < CC; c0 += 32) {
        __syncthreads();
#pragma unroll
        for (int i = 0; i < 4; ++i) {
            int flat = i * 256 + tid, rr = flat >> 3, cb = (flat & 7) * 4;
            float4 v = *(const float4*)(x + (size_t)(row0 + rr) * CC + c0 + cb);
            *(float4*)&xs[rr * 36 + cb] = v;
        }
#pragma unroll
        for (int i = 0; i < 2; ++i) {
            int f4 = i * 256 + tid;
            *(float4*)&Wst[f4 * 4] = *(const float4*)(Wc + c0 * MM + f4 * 4);
        }
        __syncthreads();
#pragma unroll
        for (int cc4 = 0; cc4 < 8; ++cc4) {
            float4 a0 = *(float4*)&xs[(r     ) * 36 + cc4 * 4];
            float4 a1 = *(float4*)&xs[(r + 64) * 36 + cc4 * 4];
            float av0[4] = {a0.x, a0.y, a0.z, a0.w};
            float av1[4] = {a1.x, a1.y, a1.z, a1.w};
#pragma unroll
            for (int k = 0; k < 4; ++k) {
                float xv0 = av0[k], xv1 = av1[k];
                const float4* wrow = (const float4*)&Wst[(cc4 * 4 + k) * 64 + h * 16];
#pragma unroll
                for (int q = 0; q < 4; ++q) {
                    float4 w = wrow[q];
                    acc[0][q * 4 + 0] += xv0 * w.x; acc[0][q * 4 + 1] += xv0 * w.y;
                    acc[0][q * 4 + 2] += xv0 * w.z; acc[0][q * 4 + 3] += xv0 * w.w;
                    acc[1][q * 4 + 0] += xv1 * w.x; acc[1][q * 4 + 1] += xv1 * w.y;
                    acc[1][q * 4 + 2] += xv1 * w.z; acc[1][q * 4 + 3] += xv1 * w.w;
                }
            }
        }
    }

    // main-phase smem dead -> stage Wes2 into smem[0..4095]
    __syncthreads();
#pragma unroll
    for (int i = 0; i < 4; ++i) {
        int f4 = i * 256 + tid;
        *(float4*)&We2[f4 * 4] = *(const float4*)(ws + WS_WES2 + f4 * 4);
    }

    float colsum[16];
#pragma unroll
    for (int j = 0; j < 16; ++j) colsum[j] = 0.f;
#pragma unroll
    for (int i = 0; i < 2; ++i) {
        float mx = -1e30f;
#pragma unroll
        for (int j = 0; j < 16; ++j) {
            int m = h * 16 + j;
            acc[i][j] = (acc[i][j] + bcs[m]) * itxs[m];
            mx = fmaxf(mx, acc[i][j]);
        }
        mx = fmaxf(mx, __shfl_xor(mx, 1));
        mx = fmaxf(mx, __shfl_xor(mx, 2));
        float s = 0.f;
#pragma unroll
        for (int j = 0; j < 16; ++j) { acc[i][j] = __expf(acc[i][j] - mx); s += acc[i][j]; }
        s += __shfl_xor(s, 1);
        s += __shfl_xor(s, 2);
        float inv = 1.f / s;
        int rl = r + 64 * i;
        int row = row0 + rl;
#pragma unroll
        for (int q = 0; q < 4; ++q) {
            float4 v = {acc[i][q * 4 + 0] * inv, acc[i][q * 4 + 1] * inv,
                        acc[i][q * 4 + 2] * inv, acc[i][q * 4 + 3] * inv};
            *(float4*)(out1 + (size_t)row * MM + h * 16 + q * 4) = v;
            *(float4*)&swl[rl * 68 + h * 16 + q * 4] = v;
#pragma unroll
            for (int j = 0; j < 4; ++j) colsum[q * 4 + j] += ((float*)&v)[j];
        }
    }
#pragma unroll
    for (int j = 0; j < 16; ++j) {
        colsum[j] += __shfl_xor(colsum[j], 4);
        colsum[j] += __shfl_xor(colsum[j], 8);
        colsum[j] += __shfl_xor(colsum[j], 16);
        colsum[j] += __shfl_xor(colsum[j], 32);
    }
    int w = tid >> 6;
    if ((tid & 63) < 4) {
#pragma unroll
        for (int j = 0; j < 16; ++j) redn[w][h * 16 + j] = colsum[j];
    }

    // ---- fused es = sw @ Wes2, all operands from LDS (no shfl) ----
    __syncthreads();
    float es0[16], es1[16];
#pragma unroll
    for (int j = 0; j < 16; ++j) { es0[j] = 0.f; es1[j] = 0.f; }
#pragma unroll 8
    for (int k = 0; k < 64; ++k) {
        float a0 = swl[(r     ) * 68 + k];
        float a1 = swl[(r + 64) * 68 + k];
        const float4* wrow = (const float4*)&We2[k * 64 + h * 16];
#pragma unroll
        for (int j = 0; j < 4; ++j) {
            float4 wv = wrow[j];
            es0[j * 4 + 0] += a0 * wv.x; es0[j * 4 + 1] += a0 * wv.y;
            es0[j * 4 + 2] += a0 * wv.z; es0[j * 4 + 3] += a0 * wv.w;
            es1[j * 4 + 0] += a1 * wv.x; es1[j * 4 + 1] += a1 * wv.y;
            es1[j * 4 + 2] += a1 * wv.z; es1[j * 4 + 3] += a1 * wv.w;
        }
    }
    {
        size_t rowA = (size_t)(row0 + r) * MM + h * 16;
        size_t rowB = (size_t)(row0 + r + 64) * MM + h * 16;
        uint4 o;
        o.x = (unsigned int)f2bf(es0[0]) | ((unsigned int)f2bf(es0[1]) << 16);
        o.y = (unsigned int)f2bf(es0[2]) | ((unsigned int)f2bf(es0[3]) << 16);
        o.z = (unsigned int)f2bf(es0[4]) | ((unsigned int)f2bf(es0[5]) << 16);
        o.w = (unsigned int)f2bf(es0[6]) | ((unsigned int)f2bf(es0[7]) << 16);
        *(uint4*)(sw2b + rowA) = o;
        o.x = (unsigned int)f2bf(es0[8])  | ((unsigned int)f2bf(es0[9])  << 16);
        o.y = (unsigned int)f2bf(es0[10]) | ((unsigned int)f2bf(es0[11]) << 16);
        o.z = (unsigned int)f2bf(es0[12]) | ((unsigned int)f2bf(es0[13]) << 16);
        o.w = (unsigned int)f2bf(es0[14]) | ((unsigned int)f2bf(es0[15]) << 16);
        *(uint4*)(sw2b + rowA + 8) = o;
        o.x = (unsigned int)f2bf(es1[0]) | ((unsigned int)f2bf(es1[1]) << 16);
        o.y = (unsigned int)f2bf(es1[2]) | ((unsigned int)f2bf(es1[3]) << 16);
        o.z = (unsigned int)f2bf(es1[4]) | ((unsigned int)f2bf(es1[5]) << 16);
        o.w = (unsigned int)f2bf(es1[6]) | ((unsigned int)f2bf(es1[7]) << 16);
        *(uint4*)(sw2b + rowB) = o;
        o.x = (unsigned int)f2bf(es1[8])  | ((unsigned int)f2bf(es1[9])  << 16);
        o.y = (unsigned int)f2bf(es1[10]) | ((unsigned int)f2bf(es1[11]) << 16);
        o.z = (unsigned int)f2bf(es1[12]) | ((unsigned int)f2bf(es1[13]) << 16);
        o.w = (unsigned int)f2bf(es1[14]) | ((unsigned int)f2bf(es1[15]) << 16);
        *(uint4*)(sw2b + rowB + 8) = o;
    }

    if (tid < 64)
        atomicAdd(&norm_acc[b * MM + tid],
                  redn[0][tid] + redn[1][tid] + redn[2][tid] + redn[3][tid]);
}

// ---------- EN2: grid-fused kN2 (blocks 0..nb2-1) + kE (256-thread, blocks nb2..) ----------
// r17: kE and kN2 both depend only on kN1 and are resource-complementary
// (gather/L2 vs LDS/FMA). One grid lets them co-schedule: ~max instead of sum.
__global__ __launch_bounds__(256, 4) void kEN2(const float* __restrict__ x,
                                               const float* __restrict__ sw,
                                               float* __restrict__ Spart,
                                               int PB, int rowsPB, int nb2,
                                               const float* __restrict__ eattr,
                                               const int* __restrict__ eidx,
                                               const unsigned short* __restrict__ sw2b,
                                               const float* __restrict__ bes,
                                               float* __restrict__ t1_acc,
                                               float* __restrict__ esn_acc) {
    __shared__ float smem[9280];   // 37.1 KB union
    const int tid = threadIdx.x;
    if ((int)blockIdx.x < nb2) {
        // ---- kN2 body (r6/r14 exact): xs = smem[0..4607] (32x144), sws = +4608 (32x64)
        float* xs  = smem;
        float* sws = smem + 4608;
        const int bid = blockIdx.x;
        const int ch = bid & 1;
        const int p = (bid >> 1) % PB, b = (bid >> 1) / PB;
        const int base = b * NN + p * rowsPB;
        const int tm = tid >> 4, tc = tid & 15;
        const int m0 = tm * 4;
        const int c0 = tc * 8;

        float acc[4][8];
#pragma unroll
        for (int mi = 0; mi < 4; ++mi)
#pragma unroll
            for (int j = 0; j < 8; ++j) acc[mi][j] = 0.f;

        for (int r0 = 0; r0 < rowsPB; r0 += 32) {
            __syncthreads();
#pragma unroll
            for (int i = 0; i < 4; ++i) {
                int flat = i * 256 + tid;
                int r = flat >> 5, c = (flat & 31) * 4;
                float4 v = *(const float4*)(x + (size_t)(base + r0 + r) * CC + ch * 128 + c);
                *(float4*)&xs[r * 144 + c + ((c >> 5) << 2)] = v;
            }
#pragma unroll
            for (int i = 0; i < 2; ++i) {
                int flat = i * 256 + tid;
                int r = flat >> 4, c = (flat & 15) * 4;
                *(float4*)&sws[r * 64 + c] = *(const float4*)(sw + (size_t)(base + r0 + r) * MM + c);
            }
            __syncthreads();
#pragma unroll 2
            for (int r = 0; r < 32; ++r) {
                float4 s4 = *(float4*)&sws[r * 64 + m0];
#pragma unroll
                for (int q = 0; q < 2; ++q) {
                    int c = c0 + q * 4;
                    float4 xv = *(float4*)&xs[r * 144 + c + ((c >> 5) << 2)];
                    acc[0][q * 4 + 0] += s4.x * xv.x; acc[0][q * 4 + 1] += s4.x * xv.y;
                    acc[0][q * 4 + 2] += s4.x * xv.z; acc[0][q * 4 + 3] += s4.x * xv.w;
                    acc[1][q * 4 + 0] += s4.y * xv.x; acc[1][q * 4 + 1] += s4.y * xv.y;
                    acc[1][q * 4 + 2] += s4.y * xv.z; acc[1][q * 4 + 3] += s4.y * xv.w;
                    acc[2][q * 4 + 0] += s4.z * xv.x; acc[2][q * 4 + 1] += s4.z * xv.y;
                    acc[2][q * 4 + 2] += s4.z * xv.z; acc[2][q * 4 + 3] += s4.z * xv.w;
                    acc[3][q * 4 + 0] += s4.w * xv.x; acc[3][q * 4 + 1] += s4.w * xv.y;
                    acc[3][q * 4 + 2] += s4.w * xv.z; acc[3][q * 4 + 3] += s4.w * xv.w;
                }
            }
        }
        float* dst = Spart + (size_t)(b * PB + p) * MM * CC + ch * 128;
#pragma unroll
        for (int mi = 0; mi < 4; ++mi)
#pragma unroll
            for (int q = 0; q < 2; ++q) {
                float4 v = {acc[mi][q * 4 + 0], acc[mi][q * 4 + 1],
                            acc[mi][q * 4 + 2], acc[mi][q * 4 + 3]};
                *(float4*)(dst + (size_t)(m0 + mi) * CC + c0 + q * 4) = v;
            }
    } else {
        // ---- kE body, 256 threads = 4 warps; u = smem[0..8447] ([4][64][33]),
        //      eav = +8448, redt = +8704, redn = +8960, bes_s = +9216
        float* u    = smem;
        float* eav  = smem + 8448;
        float* redt = smem + 8704;
        float* redn = smem + 8960;
        float* bes_s = smem + 9216;
        const int w = tid >> 6, l = tid & 63;
        const int eg = ((int)blockIdx.x - nb2) * 256 + tid;   // 262144 edges
        const int b = eg >> 16;
        if (tid < 64) bes_s[tid] = bes[tid];
        const int2 idx = ((const int2*)eidx)[eg];
        const float ea = eattr[eg];
        const uint4* g0 = (const uint4*)(sw2b + (size_t)(b * NN + idx.x) * MM);
        const uint4* g1 = (const uint4*)(sw2b + (size_t)(b * NN + idx.y) * MM);
        eav[w * 64 + l] = ea;
        __syncthreads();

        float v[64];
#pragma unroll
        for (int q = 0; q < 8; ++q) {
            uint4 a = g0[q], c = g1[q];
            unsigned int au[4] = {a.x, a.y, a.z, a.w};
            unsigned int cu[4] = {c.x, c.y, c.z, c.w};
#pragma unroll
            for (int j = 0; j < 4; ++j) {
                int m = q * 8 + j * 2;
                v[m + 0] = __uint_as_float(au[j] << 16) + __uint_as_float(cu[j] << 16) + bes_s[m + 0];
                v[m + 1] = __uint_as_float(au[j] & 0xFFFF0000u) + __uint_as_float(cu[j] & 0xFFFF0000u) + bes_s[m + 1];
            }
        }
        float mx = -1e30f;
#pragma unroll
        for (int m = 0; m < 64; ++m) mx = fmaxf(mx, v[m]);
        float s = 0.f;
#pragma unroll
        for (int m = 0; m < 64; ++m) { v[m] = __expf(v[m] - mx); s += v[m]; }
        float inv = 1.f / s;

        const int ml = l & 31, rh = l >> 5;
#pragma unroll
        for (int ph = 0; ph < 2; ++ph) {
            __syncthreads();
#pragma unroll
            for (int j = 0; j < 32; ++j) u[w * 2112 + l * 33 + j] = v[ph * 32 + j] * inv;
            __syncthreads();
            float t = 0.f, n = 0.f;
#pragma unroll 8
            for (int rr = 0; rr < 32; ++rr) {
                int r = rh * 32 + rr;
                float e = u[w * 2112 + r * 33 + ml];
                n += e;
                t += e * eav[w * 64 + r];
            }
            t += __shfl_xor(t, 32);
            n += __shfl_xor(n, 32);
            if (l < 32) { redt[w * 64 + ph * 32 + l] = t; redn[w * 64 + ph * 32 + l] = n; }
        }
        __syncthreads();
        if (tid < 64) {
            atomicAdd(&t1_acc[b * 64 + tid],
                      redt[tid] + redt[64 + tid] + redt[128 + tid] + redt[192 + tid]);
            atomicAdd(&esn_acc[b * 64 + tid],
                      redn[tid] + redn[64 + tid] + redn[128 + tid] + redn[192 + tid]);
        }
    }
}

// ---------- R: parallel partial reduce Spart -> Ssum [B,M,C] ----------
__global__ __launch_bounds__(256) void kR(const float* __restrict__ Spart,
                                          float* __restrict__ Ssum, int PB) {
    const int idx = blockIdx.x * 256 + threadIdx.x;  // B*M*C = 262144
    const int b = idx >> 14;
    const int mc = idx & 16383;
    const float* sp = Spart + (size_t)b * PB * MM * CC + mc;
    float a0 = 0.f, a1 = 0.f, a2 = 0.f, a3 = 0.f;
    for (int p = 0; p < PB; p += 4) {
        a0 += sp[(size_t)(p + 0) * MM * CC];
        a1 += sp[(size_t)(p + 1) * MM * CC];
        a2 += sp[(size_t)(p + 2) * MM * CC];
        a3 += sp[(size_t)(p + 3) * MM * CC];
    }
    Ssum[idx] = (a0 + a1) + (a2 + a3);
}

// ---------- F2: matvec + combine -> slice_token ----------
__global__ __launch_bounds__(256) void kF2(const float* __restrict__ ws,
                                           const float* __restrict__ Wfx,
                                           const float* __restrict__ bfx,
                                           const float* __restrict__ Wfe,
                                           const float* __restrict__ bfe,
                                           const float* __restrict__ phe,
                                           float* __restrict__ out0) {
    __shared__ float srow[256];
    const int bid = blockIdx.x;          // 256 blocks = (b,m)
    const int b = bid >> 6, m = bid & 63;
    const int t = threadIdx.x;
    srow[t] = ws[WS_SSUM + (size_t)(b * MM + m) * CC + t];
    __syncthreads();
    float acc = 0.f;
#pragma unroll 8
    for (int k = 0; k < 256; ++k) acc += srow[k] * Wfx[k * CC + t];
    float nv  = ws[WS_NORM + b * 64 + m];
    float t1v = ws[WS_T1   + b * 64 + m];
    float ev  = ws[WS_ESN  + b * 64 + m];
    const float scale = (float)NN / (float)EE;   // 0.25
    float num = acc + nv * bfx[t] + scale * (t1v * Wfe[t] + ev * (bfe[t] + phe[t]));
    float den = nv + scale * ev + 1e-5f;
    out0[(size_t)(b * MM + m) * CC + t] = num / den;
}

extern "C" void kernel_launch(void* const* d_in, const int* in_sizes, int n_in,
                              void* d_out, int out_size, void* d_ws, size_t ws_size,
                              hipStream_t stream) {
    const float* x     = (const float*)d_in[0];
    const float* eattr = (const float*)d_in[1];
    const int*   eidx  = (const int*)d_in[2];
    const float* Wfx   = (const float*)d_in[3];
    const float* bfx   = (const float*)d_in[4];
    const float* Wx    = (const float*)d_in[5];
    const float* bx    = (const float*)d_in[6];
    const float* Wsl   = (const float*)d_in[7];
    const float* bsl   = (const float*)d_in[8];
    const float* tx    = (const float*)d_in[9];
    const float* phx   = (const float*)d_in[10];
    const float* Wfe   = (const float*)d_in[11];
    const float* bfe   = (const float*)d_in[12];
    const float* te    = (const float*)d_in[13];
    const float* Wes   = (const float*)d_in[14];
    const float* bes   = (const float*)d_in[15];
    const float* phe   = (const float*)d_in[16];

    float* out0 = (float*)d_out;                  // slice_token [B,M,C]
    float* out1 = out0 + (size_t)BB * MM * CC;    // slice_weight [B,N,M]
    float* ws   = (float*)d_ws;
    unsigned short* sw2b = (unsigned short*)(ws + WS_SW2);

    int PB = 64;
    while (PB > 8) {
        size_t need = (size_t)(WS_SPART + (size_t)BB * PB * MM * CC) * sizeof(float);
        if (need <= ws_size) break;
        PB >>= 1;
    }
    int rowsPB = NN / PB;
    int nb2 = BB * PB * 2;                        // kN2 block count (512 @ PB=64)

    kPP<<<257, 256, 0, stream>>>(Wx, Wsl, bx, phx, bsl, tx, te, Wes, ws);
    kN1<<<512, 256, 0, stream>>>(x, ws, out1, sw2b, ws + WS_NORM);
    kEN2<<<nb2 + EE * BB / 256, 256, 0, stream>>>(x, out1, ws + WS_SPART, PB, rowsPB, nb2,
                                                  eattr, eidx, sw2b, bes,
                                                  ws + WS_T1, ws + WS_ESN);
    kR <<<1024, 256, 0, stream>>>(ws + WS_SPART, ws + WS_SSUM, PB);
    kF2<<<256, 256, 0, stream>>>(ws, Wfx, bfx, Wfe, bfe, phe, out0);
}

// Round 18
// 111.636 us; speedup vs baseline: 1.4022x; 1.1475x over previous
//
#include <hip/hip_runtime.h>

#define BB 4
#define NN 16384
#define EE 65536
#define CC 256
#define MM 64

// ws float offsets
#define WS_NORM   0                  // B*M (atomics, zeroed by kPP block 256)
#define WS_T1     256
#define WS_ESN    512
#define WS_BCOMB  768                // 64
#define WS_ITX    832                // 64
#define WS_ITE    896                // 64
#define WS_WES2   1024               // 64*64 = 4096  (itE ⊙ W_eslice)
#define WS_WCOMB  5120               // W_comb^T bf16 [64][256] = 16384 ushorts
#define WS_SW2    21504              // bf16 SW2 [B*N*M ushorts] (8MB);
#define WS_SSUM   WS_SW2             // after kEN2, overlaid by Ssum [B*M*C floats]
#define WS_SPART  4215808            // B*PB*M*C partials

typedef __attribute__((ext_vector_type(8))) __bf16 bf16x8_t;
typedef __attribute__((ext_vector_type(4))) float f32x4_t;

static __device__ __forceinline__ unsigned short f2bf(float f) {
    unsigned int u = __float_as_uint(f);
    unsigned int r = (u + 0x7FFFu + ((u >> 16) & 1u)) >> 16;   // RNE
    return (unsigned short)r;
}

// ---------- PP: merged preamble + accumulator zeroing ----------
// r18: W_comb now stored TRANSPOSED bf16 [m=64][k=256] for MFMA B-frags.
__global__ __launch_bounds__(256) void kPP(const float* __restrict__ Wx,
                                           const float* __restrict__ Wsl,
                                           const float* __restrict__ bx,
                                           const float* __restrict__ phx,
                                           const float* __restrict__ bsl,
                                           const float* __restrict__ tx,
                                           const float* __restrict__ te,
                                           const float* __restrict__ Wes,
                                           float* __restrict__ ws) {
    __shared__ float row[256];
    __shared__ float part[4][64];
    const int tid = threadIdx.x;
    const int m = tid & 63, kq = tid >> 6;
    if (blockIdx.x < 256) {
        const int c = blockIdx.x;
        row[tid] = Wx[c * CC + tid];
        __syncthreads();
        float acc = 0.f;
#pragma unroll 8
        for (int kk = 0; kk < 64; ++kk) {
            int k = kq * 64 + kk;
            acc += row[k] * Wsl[k * MM + m];
        }
        part[kq][m] = acc;
        __syncthreads();
        if (tid < 64) {
            float v = part[0][tid] + part[1][tid] + part[2][tid] + part[3][tid];
            ((unsigned short*)(ws + WS_WCOMB))[tid * 256 + c] = f2bf(v);
        }
    } else {
        // zero atomic accumulators (replaces hipMemsetAsync)
#pragma unroll
        for (int i = 0; i < 3; ++i) ws[i * 256 + tid] = 0.f;
        row[tid] = bx[tid] + phx[tid];
        __syncthreads();
        float acc = 0.f;
#pragma unroll 8
        for (int kk = 0; kk < 64; ++kk) {
            int k = kq * 64 + kk;
            acc += row[k] * Wsl[k * MM + m];
        }
        part[kq][m] = acc;
        __syncthreads();
        if (tid < 64) {
            ws[WS_BCOMB + tid] = bsl[tid] +
                part[0][tid] + part[1][tid] + part[2][tid] + part[3][tid];
            ws[WS_ITX + tid] = 1.f / fminf(fmaxf(tx[tid], 0.01f), 5.f);
            ws[WS_ITE + tid] = 1.f / fminf(fmaxf(te[tid], 0.01f), 5.f);
        }
#pragma unroll
        for (int i = 0; i < 16; ++i) {
            int e = i * 256 + tid;
            int k = e >> 6;
            float itk = 1.f / fminf(fmaxf(te[k], 0.01f), 5.f);
            ws[WS_WES2 + e] = itk * Wes[e];
        }
    }
}

// ---------- N1: MFMA x@W_comb -> softmax -> sw + norm + fused sw@Wes2 -> sw2b ----------
// r18: main loop = mfma_f32_16x16x32_bf16; A-frags loaded DIRECTLY from global
// (lane ln reads row, kg*8 window; f2bf convert) -> no per-chunk barriers at all.
// B-frags (W_comb^T bf16) staged once in LDS stride 264 (2-way conflict-free).
// D layout (verified): col=lane&15, row=(lane>>4)*4+reg -> spill to swl LDS;
// then the r12-proven epilogue (softmax + es GEMM) runs unchanged.
__global__ __launch_bounds__(256, 2) void kN1(const float* __restrict__ x,
                                              const float* __restrict__ ws,
                                              float* __restrict__ out1,
                                              unsigned short* __restrict__ sw2b,
                                              float* __restrict__ norm_acc) {
    // main: WcT bf16 [64][264] = ushorts 0..16895 (floats 0..8447)
    // epi:  We2 = smem[0..4095], swl/L = smem[4096..12799] (stride 68)
    __shared__ float smem[12800];    // 51.2 KB
    __shared__ float redn[4][64];
    __shared__ float bcs[64], itxs[64];
    unsigned short* smem_u = (unsigned short*)smem;
    float* We2 = smem;
    float* swl = smem + 4096;
    const int tid = threadIdx.x;
    const int wv = tid >> 6, l = tid & 63;
    const int ln = l & 15, kg = l >> 4;
    const int row0 = blockIdx.x * 128;
    const int b = blockIdx.x >> 7;
    const int r = tid >> 2;          // 0..63 (rows r, r+64)
    const int h = tid & 3;           // m-quarter

    if (tid < 64) { bcs[tid] = ws[WS_BCOMB + tid]; itxs[tid] = ws[WS_ITX + tid]; }

    // stage WcT (dense bf16 [64][256] in ws) -> LDS stride 264
    const unsigned short* wct = (const unsigned short*)(ws + WS_WCOMB);
#pragma unroll
    for (int i = 0; i < 8; ++i) {
        int f8 = (i * 256 + tid) * 8;
        int m = f8 >> 8, k = f8 & 255;
        *(uint4*)&smem_u[m * 264 + k] = *(const uint4*)&wct[f8];
    }
    __syncthreads();

    f32x4_t acc[2][4];
#pragma unroll
    for (int i = 0; i < 2; ++i)
#pragma unroll
        for (int j = 0; j < 4; ++j) acc[i][j] = (f32x4_t){0.f, 0.f, 0.f, 0.f};

    for (int c0 = 0; c0 < CC; c0 += 32) {
        bf16x8_t bf[4];
#pragma unroll
        for (int mt = 0; mt < 4; ++mt)
            bf[mt] = *(const bf16x8_t*)&smem_u[(mt * 16 + ln) * 264 + c0 + kg * 8];
#pragma unroll
        for (int rt = 0; rt < 2; ++rt) {
            int arow = row0 + (wv * 2 + rt) * 16 + ln;
            const float* ap = x + (size_t)arow * CC + c0 + kg * 8;
            float4 p0 = *(const float4*)ap;
            float4 p1 = *(const float4*)(ap + 4);
            union { unsigned short u[8]; bf16x8_t v; } af;
            af.u[0] = f2bf(p0.x); af.u[1] = f2bf(p0.y);
            af.u[2] = f2bf(p0.z); af.u[3] = f2bf(p0.w);
            af.u[4] = f2bf(p1.x); af.u[5] = f2bf(p1.y);
            af.u[6] = f2bf(p1.z); af.u[7] = f2bf(p1.w);
#pragma unroll
            for (int mt = 0; mt < 4; ++mt)
                acc[rt][mt] = __builtin_amdgcn_mfma_f32_16x16x32_bf16(
                    af.v, bf[mt], acc[rt][mt], 0, 0, 0);
        }
    }
    __syncthreads();   // all WcT reads done before L/We2 overwrite

    // D-frags -> L (=swl region): row=(wv*2+rt)*16+kg*4+j, col=mt*16+ln
#pragma unroll
    for (int rt = 0; rt < 2; ++rt)
#pragma unroll
        for (int mt = 0; mt < 4; ++mt)
#pragma unroll
            for (int j = 0; j < 4; ++j)
                swl[((wv * 2 + rt) * 16 + kg * 4 + j) * 68 + mt * 16 + ln] =
                    acc[rt][mt][j];
    // stage We2 into smem[0..4095]
#pragma unroll
    for (int i = 0; i < 4; ++i) {
        int f4 = i * 256 + tid;
        *(float4*)&We2[f4 * 4] = *(const float4*)(ws + WS_WES2 + f4 * 4);
    }
    __syncthreads();

    // softmax per row (quad h=0..3 shares each row), logits from L
    float sacc[2][16];
#pragma unroll
    for (int i = 0; i < 2; ++i)
#pragma unroll
        for (int q = 0; q < 4; ++q) {
            float4 v = *(float4*)&swl[(r + 64 * i) * 68 + h * 16 + q * 4];
            sacc[i][q * 4 + 0] = v.x; sacc[i][q * 4 + 1] = v.y;
            sacc[i][q * 4 + 2] = v.z; sacc[i][q * 4 + 3] = v.w;
        }
    float colsum[16];
#pragma unroll
    for (int j = 0; j < 16; ++j) colsum[j] = 0.f;
#pragma unroll
    for (int i = 0; i < 2; ++i) {
        float mx = -1e30f;
#pragma unroll
        for (int j = 0; j < 16; ++j) {
            int m = h * 16 + j;
            sacc[i][j] = (sacc[i][j] + bcs[m]) * itxs[m];
            mx = fmaxf(mx, sacc[i][j]);
        }
        mx = fmaxf(mx, __shfl_xor(mx, 1));
        mx = fmaxf(mx, __shfl_xor(mx, 2));
        float s = 0.f;
#pragma unroll
        for (int j = 0; j < 16; ++j) { sacc[i][j] = __expf(sacc[i][j] - mx); s += sacc[i][j]; }
        s += __shfl_xor(s, 1);
        s += __shfl_xor(s, 2);
        float inv = 1.f / s;
        int rl = r + 64 * i;
        int row = row0 + rl;
#pragma unroll
        for (int q = 0; q < 4; ++q) {
            float4 v = {sacc[i][q * 4 + 0] * inv, sacc[i][q * 4 + 1] * inv,
                        sacc[i][q * 4 + 2] * inv, sacc[i][q * 4 + 3] * inv};
            *(float4*)(out1 + (size_t)row * MM + h * 16 + q * 4) = v;
            *(float4*)&swl[rl * 68 + h * 16 + q * 4] = v;
#pragma unroll
            for (int j = 0; j < 4; ++j) colsum[q * 4 + j] += ((float*)&v)[j];
        }
    }
#pragma unroll
    for (int j = 0; j < 16; ++j) {
        colsum[j] += __shfl_xor(colsum[j], 4);
        colsum[j] += __shfl_xor(colsum[j], 8);
        colsum[j] += __shfl_xor(colsum[j], 16);
        colsum[j] += __shfl_xor(colsum[j], 32);
    }
    if (l < 4) {
#pragma unroll
        for (int j = 0; j < 16; ++j) redn[wv][h * 16 + j] = colsum[j];
    }

    // ---- fused es = sw @ Wes2, all operands from LDS (no shfl) ----
    __syncthreads();
    float es0[16], es1[16];
#pragma unroll
    for (int j = 0; j < 16; ++j) { es0[j] = 0.f; es1[j] = 0.f; }
#pragma unroll 8
    for (int k = 0; k < 64; ++k) {
        float a0 = swl[(r     ) * 68 + k];
        float a1 = swl[(r + 64) * 68 + k];
        const float4* wrow = (const float4*)&We2[k * 64 + h * 16];
#pragma unroll
        for (int j = 0; j < 4; ++j) {
            float4 wv4 = wrow[j];
            es0[j * 4 + 0] += a0 * wv4.x; es0[j * 4 + 1] += a0 * wv4.y;
            es0[j * 4 + 2] += a0 * wv4.z; es0[j * 4 + 3] += a0 * wv4.w;
            es1[j * 4 + 0] += a1 * wv4.x; es1[j * 4 + 1] += a1 * wv4.y;
            es1[j * 4 + 2] += a1 * wv4.z; es1[j * 4 + 3] += a1 * wv4.w;
        }
    }
    {
        size_t rowA = (size_t)(row0 + r) * MM + h * 16;
        size_t rowB = (size_t)(row0 + r + 64) * MM + h * 16;
        uint4 o;
        o.x = (unsigned int)f2bf(es0[0]) | ((unsigned int)f2bf(es0[1]) << 16);
        o.y = (unsigned int)f2bf(es0[2]) | ((unsigned int)f2bf(es0[3]) << 16);
        o.z = (unsigned int)f2bf(es0[4]) | ((unsigned int)f2bf(es0[5]) << 16);
        o.w = (unsigned int)f2bf(es0[6]) | ((unsigned int)f2bf(es0[7]) << 16);
        *(uint4*)(sw2b + rowA) = o;
        o.x = (unsigned int)f2bf(es0[8])  | ((unsigned int)f2bf(es0[9])  << 16);
        o.y = (unsigned int)f2bf(es0[10]) | ((unsigned int)f2bf(es0[11]) << 16);
        o.z = (unsigned int)f2bf(es0[12]) | ((unsigned int)f2bf(es0[13]) << 16);
        o.w = (unsigned int)f2bf(es0[14]) | ((unsigned int)f2bf(es0[15]) << 16);
        *(uint4*)(sw2b + rowA + 8) = o;
        o.x = (unsigned int)f2bf(es1[0]) | ((unsigned int)f2bf(es1[1]) << 16);
        o.y = (unsigned int)f2bf(es1[2]) | ((unsigned int)f2bf(es1[3]) << 16);
        o.z = (unsigned int)f2bf(es1[4]) | ((unsigned int)f2bf(es1[5]) << 16);
        o.w = (unsigned int)f2bf(es1[6]) | ((unsigned int)f2bf(es1[7]) << 16);
        *(uint4*)(sw2b + rowB) = o;
        o.x = (unsigned int)f2bf(es1[8])  | ((unsigned int)f2bf(es1[9])  << 16);
        o.y = (unsigned int)f2bf(es1[10]) | ((unsigned int)f2bf(es1[11]) << 16);
        o.z = (unsigned int)f2bf(es1[12]) | ((unsigned int)f2bf(es1[13]) << 16);
        o.w = (unsigned int)f2bf(es1[14]) | ((unsigned int)f2bf(es1[15]) << 16);
        *(uint4*)(sw2b + rowB + 8) = o;
    }

    if (tid < 64)
        atomicAdd(&norm_acc[b * MM + tid],
                  redn[0][tid] + redn[1][tid] + redn[2][tid] + redn[3][tid]);
}

// ---------- EN2: grid-fused kN2 (blocks 0..nb2-1) + kE (blocks nb2..) ----------
__global__ __launch_bounds__(256, 4) void kEN2(const float* __restrict__ x,
                                               const float* __restrict__ sw,
                                               float* __restrict__ Spart,
                                               int PB, int rowsPB, int nb2,
                                               const float* __restrict__ eattr,
                                               const int* __restrict__ eidx,
                                               const unsigned short* __restrict__ sw2b,
                                               const float* __restrict__ bes,
                                               float* __restrict__ t1_acc,
                                               float* __restrict__ esn_acc) {
    __shared__ float smem[9280];   // 37.1 KB union
    const int tid = threadIdx.x;
    if ((int)blockIdx.x < nb2) {
        float* xs  = smem;
        float* sws = smem + 4608;
        const int bid = blockIdx.x;
        const int ch = bid & 1;
        const int p = (bid >> 1) % PB, b = (bid >> 1) / PB;
        const int base = b * NN + p * rowsPB;
        const int tm = tid >> 4, tc = tid & 15;
        const int m0 = tm * 4;
        const int c0 = tc * 8;

        float acc[4][8];
#pragma unroll
        for (int mi = 0; mi < 4; ++mi)
#pragma unroll
            for (int j = 0; j < 8; ++j) acc[mi][j] = 0.f;

        for (int r0 = 0; r0 < rowsPB; r0 += 32) {
            __syncthreads();
#pragma unroll
            for (int i = 0; i < 4; ++i) {
                int flat = i * 256 + tid;
                int r = flat >> 5, c = (flat & 31) * 4;
                float4 v = *(const float4*)(x + (size_t)(base + r0 + r) * CC + ch * 128 + c);
                *(float4*)&xs[r * 144 + c + ((c >> 5) << 2)] = v;
            }
#pragma unroll
            for (int i = 0; i < 2; ++i) {
                int flat = i * 256 + tid;
                int r = flat >> 4, c = (flat & 15) * 4;
                *(float4*)&sws[r * 64 + c] = *(const float4*)(sw + (size_t)(base + r0 + r) * MM + c);
            }
            __syncthreads();
#pragma unroll 2
            for (int r = 0; r < 32; ++r) {
                float4 s4 = *(float4*)&sws[r * 64 + m0];
#pragma unroll
                for (int q = 0; q < 2; ++q) {
                    int c = c0 + q * 4;
                    float4 xv = *(float4*)&xs[r * 144 + c + ((c >> 5) << 2)];
                    acc[0][q * 4 + 0] += s4.x * xv.x; acc[0][q * 4 + 1] += s4.x * xv.y;
                    acc[0][q * 4 + 2] += s4.x * xv.z; acc[0][q * 4 + 3] += s4.x * xv.w;
                    acc[1][q * 4 + 0] += s4.y * xv.x; acc[1][q * 4 + 1] += s4.y * xv.y;
                    acc[1][q * 4 + 2] += s4.y * xv.z; acc[1][q * 4 + 3] += s4.y * xv.w;
                    acc[2][q * 4 + 0] += s4.z * xv.x; acc[2][q * 4 + 1] += s4.z * xv.y;
                    acc[2][q * 4 + 2] += s4.z * xv.z; acc[2][q * 4 + 3] += s4.z * xv.w;
                    acc[3][q * 4 + 0] += s4.w * xv.x; acc[3][q * 4 + 1] += s4.w * xv.y;
                    acc[3][q * 4 + 2] += s4.w * xv.z; acc[3][q * 4 + 3] += s4.w * xv.w;
                }
            }
        }
        float* dst = Spart + (size_t)(b * PB + p) * MM * CC + ch * 128;
#pragma unroll
        for (int mi = 0; mi < 4; ++mi)
#pragma unroll
            for (int q = 0; q < 2; ++q) {
                float4 v = {acc[mi][q * 4 + 0], acc[mi][q * 4 + 1],
                            acc[mi][q * 4 + 2], acc[mi][q * 4 + 3]};
                *(float4*)(dst + (size_t)(m0 + mi) * CC + c0 + q * 4) = v;
            }
    } else {
        float* u    = smem;
        float* eav  = smem + 8448;
        float* redt = smem + 8704;
        float* redn = smem + 8960;
        float* bes_s = smem + 9216;
        const int w = tid >> 6, l = tid & 63;
        const int eg = ((int)blockIdx.x - nb2) * 256 + tid;
        const int b = eg >> 16;
        if (tid < 64) bes_s[tid] = bes[tid];
        const int2 idx = ((const int2*)eidx)[eg];
        const float ea = eattr[eg];
        const uint4* g0 = (const uint4*)(sw2b + (size_t)(b * NN + idx.x) * MM);
        const uint4* g1 = (const uint4*)(sw2b + (size_t)(b * NN + idx.y) * MM);
        eav[w * 64 + l] = ea;
        __syncthreads();

        float v[64];
#pragma unroll
        for (int q = 0; q < 8; ++q) {
            uint4 a = g0[q], c = g1[q];
            unsigned int au[4] = {a.x, a.y, a.z, a.w};
            unsigned int cu[4] = {c.x, c.y, c.z, c.w};
#pragma unroll
            for (int j = 0; j < 4; ++j) {
                int m = q * 8 + j * 2;
                v[m + 0] = __uint_as_float(au[j] << 16) + __uint_as_float(cu[j] << 16) + bes_s[m + 0];
                v[m + 1] = __uint_as_float(au[j] & 0xFFFF0000u) + __uint_as_float(cu[j] & 0xFFFF0000u) + bes_s[m + 1];
            }
        }
        float mx = -1e30f;
#pragma unroll
        for (int m = 0; m < 64; ++m) mx = fmaxf(mx, v[m]);
        float s = 0.f;
#pragma unroll
        for (int m = 0; m < 64; ++m) { v[m] = __expf(v[m] - mx); s += v[m]; }
        float inv = 1.f / s;

        const int ml = l & 31, rh = l >> 5;
#pragma unroll
        for (int ph = 0; ph < 2; ++ph) {
            __syncthreads();
#pragma unroll
            for (int j = 0; j < 32; ++j) u[w * 2112 + l * 33 + j] = v[ph * 32 + j] * inv;
            __syncthreads();
            float t = 0.f, n = 0.f;
#pragma unroll 8
            for (int rr = 0; rr < 32; ++rr) {
                int r = rh * 32 + rr;
                float e = u[w * 2112 + r * 33 + ml];
                n += e;
                t += e * eav[w * 64 + r];
            }
            t += __shfl_xor(t, 32);
            n += __shfl_xor(n, 32);
            if (l < 32) { redt[w * 64 + ph * 32 + l] = t; redn[w * 64 + ph * 32 + l] = n; }
        }
        __syncthreads();
        if (tid < 64) {
            atomicAdd(&t1_acc[b * 64 + tid],
                      redt[tid] + redt[64 + tid] + redt[128 + tid] + redt[192 + tid]);
            atomicAdd(&esn_acc[b * 64 + tid],
                      redn[tid] + redn[64 + tid] + redn[128 + tid] + redn[192 + tid]);
        }
    }
}

// ---------- R: parallel partial reduce Spart -> Ssum [B,M,C] ----------
__global__ __launch_bounds__(256) void kR(const float* __restrict__ Spart,
                                          float* __restrict__ Ssum, int PB) {
    const int idx = blockIdx.x * 256 + threadIdx.x;
    const int b = idx >> 14;
    const int mc = idx & 16383;
    const float* sp = Spart + (size_t)b * PB * MM * CC + mc;
    float a0 = 0.f, a1 = 0.f, a2 = 0.f, a3 = 0.f;
    for (int p = 0; p < PB; p += 4) {
        a0 += sp[(size_t)(p + 0) * MM * CC];
        a1 += sp[(size_t)(p + 1) * MM * CC];
        a2 += sp[(size_t)(p + 2) * MM * CC];
        a3 += sp[(size_t)(p + 3) * MM * CC];
    }
    Ssum[idx] = (a0 + a1) + (a2 + a3);
}

// ---------- F2: matvec + combine -> slice_token ----------
__global__ __launch_bounds__(256) void kF2(const float* __restrict__ ws,
                                           const float* __restrict__ Wfx,
                                           const float* __restrict__ bfx,
                                           const float* __restrict__ Wfe,
                                           const float* __restrict__ bfe,
                                           const float* __restrict__ phe,
                                           float* __restrict__ out0) {
    __shared__ float srow[256];
    const int bid = blockIdx.x;
    const int b = bid >> 6, m = bid & 63;
    const int t = threadIdx.x;
    srow[t] = ws[WS_SSUM + (size_t)(b * MM + m) * CC + t];
    __syncthreads();
    float acc = 0.f;
#pragma unroll 8
    for (int k = 0; k < 256; ++k) acc += srow[k] * Wfx[k * CC + t];
    float nv  = ws[WS_NORM + b * 64 + m];
    float t1v = ws[WS_T1   + b * 64 + m];
    float ev  = ws[WS_ESN  + b * 64 + m];
    const float scale = (float)NN / (float)EE;   // 0.25
    float num = acc + nv * bfx[t] + scale * (t1v * Wfe[t] + ev * (bfe[t] + phe[t]));
    float den = nv + scale * ev + 1e-5f;
    out0[(size_t)(b * MM + m) * CC + t] = num / den;
}

extern "C" void kernel_launch(void* const* d_in, const int* in_sizes, int n_in,
                              void* d_out, int out_size, void* d_ws, size_t ws_size,
                              hipStream_t stream) {
    const float* x     = (const float*)d_in[0];
    const float* eattr = (const float*)d_in[1];
    const int*   eidx  = (const int*)d_in[2];
    const float* Wfx   = (const float*)d_in[3];
    const float* bfx   = (const float*)d_in[4];
    const float* Wx    = (const float*)d_in[5];
    const float* bx    = (const float*)d_in[6];
    const float* Wsl   = (const float*)d_in[7];
    const float* bsl   = (const float*)d_in[8];
    const float* tx    = (const float*)d_in[9];
    const float* phx   = (const float*)d_in[10];
    const float* Wfe   = (const float*)d_in[11];
    const float* bfe   = (const float*)d_in[12];
    const float* te    = (const float*)d_in[13];
    const float* Wes   = (const float*)d_in[14];
    const float* bes   = (const float*)d_in[15];
    const float* phe   = (const float*)d_in[16];

    float* out0 = (float*)d_out;                  // slice_token [B,M,C]
    float* out1 = out0 + (size_t)BB * MM * CC;    // slice_weight [B,N,M]
    float* ws   = (float*)d_ws;
    unsigned short* sw2b = (unsigned short*)(ws + WS_SW2);

    int PB = 64;
    while (PB > 8) {
        size_t need = (size_t)(WS_SPART + (size_t)BB * PB * MM * CC) * sizeof(float);
        if (need <= ws_size) break;
        PB >>= 1;
    }
    int rowsPB = NN / PB;
    int nb2 = BB * PB * 2;

    kPP<<<257, 256, 0, stream>>>(Wx, Wsl, bx, phx, bsl, tx, te, Wes, ws);
    kN1<<<512, 256, 0, stream>>>(x, ws, out1, sw2b, ws + WS_NORM);
    kEN2<<<nb2 + EE * BB / 256, 256, 0, stream>>>(x, out1, ws + WS_SPART, PB, rowsPB, nb2,
                                                  eattr, eidx, sw2b, bes,
                                                  ws + WS_T1, ws + WS_ESN);
    kR <<<1024, 256, 0, stream>>>(ws + WS_SPART, ws + WS_SSUM, PB);
    kF2<<<256, 256, 0, stream>>>(ws, Wfx, bfx, Wfe, bfe, phe, out0);
}

// Round 19
// 104.077 us; speedup vs baseline: 1.5041x; 1.0726x over previous
//
#include <hip/hip_runtime.h>

#define BB 4
#define NN 16384
#define EE 65536
#define CC 256
#define MM 64

// ws float offsets
#define WS_NORM   0                  // B*M (atomics, zeroed by kPP block 256)
#define WS_T1     256
#define WS_ESN    512
#define WS_BCOMB  768                // 64
#define WS_ITX    832                // 64
#define WS_ITE    896                // 64
#define WS_WES2   1024               // 64*64 fp32 (unused by kN1 now; kept)
#define WS_WCOMB  5120               // W_comb^T bf16 [64][256] = 16384 u16 = 8192 floats
#define WS_WES2T  13312              // Wes2^T bf16 [m=64][k=64] = 4096 u16 = 2048 floats
#define WS_SW2    21504              // bf16 SW2 [B*N*M ushorts] (8MB)
#define WS_SSUM   WS_SW2             // after kEN2, overlaid by Ssum [B*M*C floats]
#define WS_SPART  4215808            // B*PB*M*C partials

typedef __attribute__((ext_vector_type(8))) __bf16 bf16x8_t;
typedef __attribute__((ext_vector_type(4))) float f32x4_t;

static __device__ __forceinline__ unsigned short f2bf(float f) {
    unsigned int u = __float_as_uint(f);
    unsigned int r = (u + 0x7FFFu + ((u >> 16) & 1u)) >> 16;   // RNE
    return (unsigned short)r;
}

// ---------- PP: merged preamble + accumulator zeroing ----------
__global__ __launch_bounds__(256) void kPP(const float* __restrict__ Wx,
                                           const float* __restrict__ Wsl,
                                           const float* __restrict__ bx,
                                           const float* __restrict__ phx,
                                           const float* __restrict__ bsl,
                                           const float* __restrict__ tx,
                                           const float* __restrict__ te,
                                           const float* __restrict__ Wes,
                                           float* __restrict__ ws) {
    __shared__ float row[256];
    __shared__ float part[4][64];
    const int tid = threadIdx.x;
    const int m = tid & 63, kq = tid >> 6;
    if (blockIdx.x < 256) {
        const int c = blockIdx.x;
        row[tid] = Wx[c * CC + tid];
        __syncthreads();
        float acc = 0.f;
#pragma unroll 8
        for (int kk = 0; kk < 64; ++kk) {
            int k = kq * 64 + kk;
            acc += row[k] * Wsl[k * MM + m];
        }
        part[kq][m] = acc;
        __syncthreads();
        if (tid < 64) {
            float v = part[0][tid] + part[1][tid] + part[2][tid] + part[3][tid];
            ((unsigned short*)(ws + WS_WCOMB))[tid * 256 + c] = f2bf(v);
        }
    } else {
#pragma unroll
        for (int i = 0; i < 3; ++i) ws[i * 256 + tid] = 0.f;
        row[tid] = bx[tid] + phx[tid];
        __syncthreads();
        float acc = 0.f;
#pragma unroll 8
        for (int kk = 0; kk < 64; ++kk) {
            int k = kq * 64 + kk;
            acc += row[k] * Wsl[k * MM + m];
        }
        part[kq][m] = acc;
        __syncthreads();
        if (tid < 64) {
            ws[WS_BCOMB + tid] = bsl[tid] +
                part[0][tid] + part[1][tid] + part[2][tid] + part[3][tid];
            ws[WS_ITX + tid] = 1.f / fminf(fmaxf(tx[tid], 0.01f), 5.f);
            ws[WS_ITE + tid] = 1.f / fminf(fmaxf(te[tid], 0.01f), 5.f);
        }
        // Wes2T bf16 [m][k] = itE[k] * Wes[k][m]  (for kN1's es-MFMA B-frags)
        unsigned short* w2t = (unsigned short*)(ws + WS_WES2T);
#pragma unroll
        for (int i = 0; i < 16; ++i) {
            int e = i * 256 + tid;
            int m2 = e >> 6, k2 = e & 63;
            float itk = 1.f / fminf(fmaxf(te[k2], 0.01f), 5.f);
            w2t[m2 * 64 + k2] = f2bf(itk * Wes[k2 * 64 + m2]);
        }
    }
}

// ---------- N1: MFMA x@W_comb -> softmax -> sw + norm + MFMA sw@Wes2 -> sw2b ----------
// r18 main loop (proven, 51us total); r19 replaces the fp32 es-GEMM epilogue
// (384 LDS instr/wave) with a 16-MFMA es-GEMM: A from swl fp32 (+f2bf), B from
// Wes2T bf16 (LDS stride 80), D-frags -> esb bf16 -> coalesced sw2b stores.
__global__ __launch_bounds__(256, 2) void kN1(const float* __restrict__ x,
                                              const float* __restrict__ ws,
                                              float* __restrict__ out1,
                                              unsigned short* __restrict__ sw2b,
                                              float* __restrict__ norm_acc) {
    // main: WcT u16 at floats 0..8447 (stride 264 u16)
    // epi:  w2t u16 at floats 0..2559 ([64][80] u16); swl fp32 at 4096..12799
    //       (stride 68); esb u16 at floats 12800..17919 ([128][80] u16)
    __shared__ float smem[17920];    // 71.7 KB
    __shared__ float redn[4][64];
    __shared__ float bcs[64], itxs[64];
    unsigned short* smem_u = (unsigned short*)smem;
    float* swl = smem + 4096;
    const int tid = threadIdx.x;
    const int wv = tid >> 6, l = tid & 63;
    const int ln = l & 15, kg = l >> 4;
    const int row0 = blockIdx.x * 128;
    const int b = blockIdx.x >> 7;
    const int r = tid >> 2;          // 0..63 (rows r, r+64)
    const int h = tid & 3;           // m-quarter

    if (tid < 64) { bcs[tid] = ws[WS_BCOMB + tid]; itxs[tid] = ws[WS_ITX + tid]; }

    // stage WcT (dense bf16 [64][256] in ws) -> LDS stride 264
    const unsigned short* wct = (const unsigned short*)(ws + WS_WCOMB);
#pragma unroll
    for (int i = 0; i < 8; ++i) {
        int f8 = (i * 256 + tid) * 8;
        int m = f8 >> 8, k = f8 & 255;
        *(uint4*)&smem_u[m * 264 + k] = *(const uint4*)&wct[f8];
    }
    __syncthreads();

    f32x4_t acc[2][4];
#pragma unroll
    for (int i = 0; i < 2; ++i)
#pragma unroll
        for (int j = 0; j < 4; ++j) acc[i][j] = (f32x4_t){0.f, 0.f, 0.f, 0.f};

    for (int c0 = 0; c0 < CC; c0 += 32) {
        bf16x8_t bf[4];
#pragma unroll
        for (int mt = 0; mt < 4; ++mt)
            bf[mt] = *(const bf16x8_t*)&smem_u[(mt * 16 + ln) * 264 + c0 + kg * 8];
#pragma unroll
        for (int rt = 0; rt < 2; ++rt) {
            int arow = row0 + (wv * 2 + rt) * 16 + ln;
            const float* ap = x + (size_t)arow * CC + c0 + kg * 8;
            float4 p0 = *(const float4*)ap;
            float4 p1 = *(const float4*)(ap + 4);
            union { unsigned short u[8]; bf16x8_t v; } af;
            af.u[0] = f2bf(p0.x); af.u[1] = f2bf(p0.y);
            af.u[2] = f2bf(p0.z); af.u[3] = f2bf(p0.w);
            af.u[4] = f2bf(p1.x); af.u[5] = f2bf(p1.y);
            af.u[6] = f2bf(p1.z); af.u[7] = f2bf(p1.w);
#pragma unroll
            for (int mt = 0; mt < 4; ++mt)
                acc[rt][mt] = __builtin_amdgcn_mfma_f32_16x16x32_bf16(
                    af.v, bf[mt], acc[rt][mt], 0, 0, 0);
        }
    }
    __syncthreads();   // all WcT reads done

    // D-frags -> swl fp32 (logits); stage w2t bf16 into dead WcT region
#pragma unroll
    for (int rt = 0; rt < 2; ++rt)
#pragma unroll
        for (int mt = 0; mt < 4; ++mt)
#pragma unroll
            for (int j = 0; j < 4; ++j)
                swl[((wv * 2 + rt) * 16 + kg * 4 + j) * 68 + mt * 16 + ln] =
                    acc[rt][mt][j];
    {
        const unsigned short* w2tg = (const unsigned short*)(ws + WS_WES2T);
        int m2 = tid >> 2, k2 = (tid & 3) * 16;
        *(uint4*)&smem_u[m2 * 80 + k2] = *(const uint4*)&w2tg[m2 * 64 + k2];
        *(uint4*)&smem_u[m2 * 80 + k2 + 8] = *(const uint4*)&w2tg[m2 * 64 + k2 + 8];
    }
    __syncthreads();

    // softmax per row (quad h=0..3 shares each row), logits from swl
    float sacc[2][16];
#pragma unroll
    for (int i = 0; i < 2; ++i)
#pragma unroll
        for (int q = 0; q < 4; ++q) {
            float4 v = *(float4*)&swl[(r + 64 * i) * 68 + h * 16 + q * 4];
            sacc[i][q * 4 + 0] = v.x; sacc[i][q * 4 + 1] = v.y;
            sacc[i][q * 4 + 2] = v.z; sacc[i][q * 4 + 3] = v.w;
        }
    float colsum[16];
#pragma unroll
    for (int j = 0; j < 16; ++j) colsum[j] = 0.f;
#pragma unroll
    for (int i = 0; i < 2; ++i) {
        float mx = -1e30f;
#pragma unroll
        for (int j = 0; j < 16; ++j) {
            int m = h * 16 + j;
            sacc[i][j] = (sacc[i][j] + bcs[m]) * itxs[m];
            mx = fmaxf(mx, sacc[i][j]);
        }
        mx = fmaxf(mx, __shfl_xor(mx, 1));
        mx = fmaxf(mx, __shfl_xor(mx, 2));
        float s = 0.f;
#pragma unroll
        for (int j = 0; j < 16; ++j) { sacc[i][j] = __expf(sacc[i][j] - mx); s += sacc[i][j]; }
        s += __shfl_xor(s, 1);
        s += __shfl_xor(s, 2);
        float inv = 1.f / s;
        int rl = r + 64 * i;
        int row = row0 + rl;
#pragma unroll
        for (int q = 0; q < 4; ++q) {
            float4 v = {sacc[i][q * 4 + 0] * inv, sacc[i][q * 4 + 1] * inv,
                        sacc[i][q * 4 + 2] * inv, sacc[i][q * 4 + 3] * inv};
            *(float4*)(out1 + (size_t)row * MM + h * 16 + q * 4) = v;
            *(float4*)&swl[rl * 68 + h * 16 + q * 4] = v;
#pragma unroll
            for (int j = 0; j < 4; ++j) colsum[q * 4 + j] += ((float*)&v)[j];
        }
    }
#pragma unroll
    for (int j = 0; j < 16; ++j) {
        colsum[j] += __shfl_xor(colsum[j], 4);
        colsum[j] += __shfl_xor(colsum[j], 8);
        colsum[j] += __shfl_xor(colsum[j], 16);
        colsum[j] += __shfl_xor(colsum[j], 32);
    }
    if (l < 4) {
#pragma unroll
        for (int j = 0; j < 16; ++j) redn[wv][h * 16 + j] = colsum[j];
    }
    __syncthreads();   // sw in swl + w2t staged + redn written

    // ---- es = sw @ Wes2 via MFMA (A: swl fp32 + f2bf; B: w2t bf16) ----
    f32x4_t eacc[2][4];
#pragma unroll
    for (int i = 0; i < 2; ++i)
#pragma unroll
        for (int j = 0; j < 4; ++j) eacc[i][j] = (f32x4_t){0.f, 0.f, 0.f, 0.f};
#pragma unroll
    for (int ks = 0; ks < 2; ++ks) {
        bf16x8_t bfw[4];
#pragma unroll
        for (int mt = 0; mt < 4; ++mt)
            bfw[mt] = *(const bf16x8_t*)&smem_u[(mt * 16 + ln) * 80 + ks * 32 + kg * 8];
#pragma unroll
        for (int rt = 0; rt < 2; ++rt) {
            const float* ap = &swl[((wv * 2 + rt) * 16 + ln) * 68 + ks * 32 + kg * 8];
            float4 p0 = *(const float4*)ap;
            float4 p1 = *(const float4*)(ap + 4);
            union { unsigned short u[8]; bf16x8_t v; } af;
            af.u[0] = f2bf(p0.x); af.u[1] = f2bf(p0.y);
            af.u[2] = f2bf(p0.z); af.u[3] = f2bf(p0.w);
            af.u[4] = f2bf(p1.x); af.u[5] = f2bf(p1.y);
            af.u[6] = f2bf(p1.z); af.u[7] = f2bf(p1.w);
#pragma unroll
            for (int mt = 0; mt < 4; ++mt)
                eacc[rt][mt] = __builtin_amdgcn_mfma_f32_16x16x32_bf16(
                    af.v, bfw[mt], eacc[rt][mt], 0, 0, 0);
        }
    }
    // D-frags -> esb bf16 ([128][80] u16 at float offset 12800)
    {
        unsigned short* esb = (unsigned short*)(smem + 12800);
#pragma unroll
        for (int rt = 0; rt < 2; ++rt)
#pragma unroll
            for (int mt = 0; mt < 4; ++mt)
#pragma unroll
                for (int j = 0; j < 4; ++j)
                    esb[((wv * 2 + rt) * 16 + kg * 4 + j) * 80 + mt * 16 + ln] =
                        f2bf(eacc[rt][mt][j]);
    }
    __syncthreads();
    // coalesced esb -> sw2b (64B per thread)
    {
        const unsigned short* esb = (const unsigned short*)(smem + 12800);
        int row = tid >> 1, half = tid & 1;
        const uint4* src = (const uint4*)&esb[row * 80 + half * 32];
        uint4* dst = (uint4*)(sw2b + (size_t)(row0 + row) * MM + half * 32);
        dst[0] = src[0]; dst[1] = src[1]; dst[2] = src[2]; dst[3] = src[3];
    }

    if (tid < 64)
        atomicAdd(&norm_acc[b * MM + tid],
                  redn[0][tid] + redn[1][tid] + redn[2][tid] + redn[3][tid]);
}

// ---------- EN2: grid-fused kN2 (blocks 0..nb2-1) + kE (blocks nb2..) ----------
__global__ __launch_bounds__(256, 4) void kEN2(const float* __restrict__ x,
                                               const float* __restrict__ sw,
                                               float* __restrict__ Spart,
                                               int PB, int rowsPB, int nb2,
                                               const float* __restrict__ eattr,
                                               const int* __restrict__ eidx,
                                               const unsigned short* __restrict__ sw2b,
                                               const float* __restrict__ bes,
                                               float* __restrict__ t1_acc,
                                               float* __restrict__ esn_acc) {
    __shared__ float smem[9280];   // 37.1 KB union
    const int tid = threadIdx.x;
    if ((int)blockIdx.x < nb2) {
        float* xs  = smem;
        float* sws = smem + 4608;
        const int bid = blockIdx.x;
        const int ch = bid & 1;
        const int p = (bid >> 1) % PB, b = (bid >> 1) / PB;
        const int base = b * NN + p * rowsPB;
        const int tm = tid >> 4, tc = tid & 15;
        const int m0 = tm * 4;
        const int c0 = tc * 8;

        float acc[4][8];
#pragma unroll
        for (int mi = 0; mi < 4; ++mi)
#pragma unroll
            for (int j = 0; j < 8; ++j) acc[mi][j] = 0.f;

        for (int r0 = 0; r0 < rowsPB; r0 += 32) {
            __syncthreads();
#pragma unroll
            for (int i = 0; i < 4; ++i) {
                int flat = i * 256 + tid;
                int r = flat >> 5, c = (flat & 31) * 4;
                float4 v = *(const float4*)(x + (size_t)(base + r0 + r) * CC + ch * 128 + c);
                *(float4*)&xs[r * 144 + c + ((c >> 5) << 2)] = v;
            }
#pragma unroll
            for (int i = 0; i < 2; ++i) {
                int flat = i * 256 + tid;
                int r = flat >> 4, c = (flat & 15) * 4;
                *(float4*)&sws[r * 64 + c] = *(const float4*)(sw + (size_t)(base + r0 + r) * MM + c);
            }
            __syncthreads();
#pragma unroll 2
            for (int r = 0; r < 32; ++r) {
                float4 s4 = *(float4*)&sws[r * 64 + m0];
#pragma unroll
                for (int q = 0; q < 2; ++q) {
                    int c = c0 + q * 4;
                    float4 xv = *(float4*)&xs[r * 144 + c + ((c >> 5) << 2)];
                    acc[0][q * 4 + 0] += s4.x * xv.x; acc[0][q * 4 + 1] += s4.x * xv.y;
                    acc[0][q * 4 + 2] += s4.x * xv.z; acc[0][q * 4 + 3] += s4.x * xv.w;
                    acc[1][q * 4 + 0] += s4.y * xv.x; acc[1][q * 4 + 1] += s4.y * xv.y;
                    acc[1][q * 4 + 2] += s4.y * xv.z; acc[1][q * 4 + 3] += s4.y * xv.w;
                    acc[2][q * 4 + 0] += s4.z * xv.x; acc[2][q * 4 + 1] += s4.z * xv.y;
                    acc[2][q * 4 + 2] += s4.z * xv.z; acc[2][q * 4 + 3] += s4.z * xv.w;
                    acc[3][q * 4 + 0] += s4.w * xv.x; acc[3][q * 4 + 1] += s4.w * xv.y;
                    acc[3][q * 4 + 2] += s4.w * xv.z; acc[3][q * 4 + 3] += s4.w * xv.w;
                }
            }
        }
        float* dst = Spart + (size_t)(b * PB + p) * MM * CC + ch * 128;
#pragma unroll
        for (int mi = 0; mi < 4; ++mi)
#pragma unroll
            for (int q = 0; q < 2; ++q) {
                float4 v = {acc[mi][q * 4 + 0], acc[mi][q * 4 + 1],
                            acc[mi][q * 4 + 2], acc[mi][q * 4 + 3]};
                *(float4*)(dst + (size_t)(m0 + mi) * CC + c0 + q * 4) = v;
            }
    } else {
        float* u    = smem;
        float* eav  = smem + 8448;
        float* redt = smem + 8704;
        float* redn = smem + 8960;
        float* bes_s = smem + 9216;
        const int w = tid >> 6, l = tid & 63;
        const int eg = ((int)blockIdx.x - nb2) * 256 + tid;
        const int b = eg >> 16;
        if (tid < 64) bes_s[tid] = bes[tid];
        const int2 idx = ((const int2*)eidx)[eg];
        const float ea = eattr[eg];
        const uint4* g0 = (const uint4*)(sw2b + (size_t)(b * NN + idx.x) * MM);
        const uint4* g1 = (const uint4*)(sw2b + (size_t)(b * NN + idx.y) * MM);
        eav[w * 64 + l] = ea;
        __syncthreads();

        float v[64];
#pragma unroll
        for (int q = 0; q < 8; ++q) {
            uint4 a = g0[q], c = g1[q];
            unsigned int au[4] = {a.x, a.y, a.z, a.w};
            unsigned int cu[4] = {c.x, c.y, c.z, c.w};
#pragma unroll
            for (int j = 0; j < 4; ++j) {
                int m = q * 8 + j * 2;
                v[m + 0] = __uint_as_float(au[j] << 16) + __uint_as_float(cu[j] << 16) + bes_s[m + 0];
                v[m + 1] = __uint_as_float(au[j] & 0xFFFF0000u) + __uint_as_float(cu[j] & 0xFFFF0000u) + bes_s[m + 1];
            }
        }
        float mx = -1e30f;
#pragma unroll
        for (int m = 0; m < 64; ++m) mx = fmaxf(mx, v[m]);
        float s = 0.f;
#pragma unroll
        for (int m = 0; m < 64; ++m) { v[m] = __expf(v[m] - mx); s += v[m]; }
        float inv = 1.f / s;

        const int ml = l & 31, rh = l >> 5;
#pragma unroll
        for (int ph = 0; ph < 2; ++ph) {
            __syncthreads();
#pragma unroll
            for (int j = 0; j < 32; ++j) u[w * 2112 + l * 33 + j] = v[ph * 32 + j] * inv;
            __syncthreads();
            float t = 0.f, n = 0.f;
#pragma unroll 8
            for (int rr = 0; rr < 32; ++rr) {
                int r = rh * 32 + rr;
                float e = u[w * 2112 + r * 33 + ml];
                n += e;
                t += e * eav[w * 64 + r];
            }
            t += __shfl_xor(t, 32);
            n += __shfl_xor(n, 32);
            if (l < 32) { redt[w * 64 + ph * 32 + l] = t; redn[w * 64 + ph * 32 + l] = n; }
        }
        __syncthreads();
        if (tid < 64) {
            atomicAdd(&t1_acc[b * 64 + tid],
                      redt[tid] + redt[64 + tid] + redt[128 + tid] + redt[192 + tid]);
            atomicAdd(&esn_acc[b * 64 + tid],
                      redn[tid] + redn[64 + tid] + redn[128 + tid] + redn[192 + tid]);
        }
    }
}

// ---------- R: parallel partial reduce Spart -> Ssum [B,M,C] ----------
__global__ __launch_bounds__(256) void kR(const float* __restrict__ Spart,
                                          float* __restrict__ Ssum, int PB) {
    const int idx = blockIdx.x * 256 + threadIdx.x;
    const int b = idx >> 14;
    const int mc = idx & 16383;
    const float* sp = Spart + (size_t)b * PB * MM * CC + mc;
    float a0 = 0.f, a1 = 0.f, a2 = 0.f, a3 = 0.f;
    for (int p = 0; p < PB; p += 4) {
        a0 += sp[(size_t)(p + 0) * MM * CC];
        a1 += sp[(size_t)(p + 1) * MM * CC];
        a2 += sp[(size_t)(p + 2) * MM * CC];
        a3 += sp[(size_t)(p + 3) * MM * CC];
    }
    Ssum[idx] = (a0 + a1) + (a2 + a3);
}

// ---------- F2: matvec + combine -> slice_token ----------
__global__ __launch_bounds__(256) void kF2(const float* __restrict__ ws,
                                           const float* __restrict__ Wfx,
                                           const float* __restrict__ bfx,
                                           const float* __restrict__ Wfe,
                                           const float* __restrict__ bfe,
                                           const float* __restrict__ phe,
                                           float* __restrict__ out0) {
    __shared__ float srow[256];
    const int bid = blockIdx.x;
    const int b = bid >> 6, m = bid & 63;
    const int t = threadIdx.x;
    srow[t] = ws[WS_SSUM + (size_t)(b * MM + m) * CC + t];
    __syncthreads();
    float acc = 0.f;
#pragma unroll 8
    for (int k = 0; k < 256; ++k) acc += srow[k] * Wfx[k * CC + t];
    float nv  = ws[WS_NORM + b * 64 + m];
    float t1v = ws[WS_T1   + b * 64 + m];
    float ev  = ws[WS_ESN  + b * 64 + m];
    const float scale = (float)NN / (float)EE;   // 0.25
    float num = acc + nv * bfx[t] + scale * (t1v * Wfe[t] + ev * (bfe[t] + phe[t]));
    float den = nv + scale * ev + 1e-5f;
    out0[(size_t)(b * MM + m) * CC + t] = num / den;
}

extern "C" void kernel_launch(void* const* d_in, const int* in_sizes, int n_in,
                              void* d_out, int out_size, void* d_ws, size_t ws_size,
                              hipStream_t stream) {
    const float* x     = (const float*)d_in[0];
    const float* eattr = (const float*)d_in[1];
    const int*   eidx  = (const int*)d_in[2];
    const float* Wfx   = (const float*)d_in[3];
    const float* bfx   = (const float*)d_in[4];
    const float* Wx    = (const float*)d_in[5];
    const float* bx    = (const float*)d_in[6];
    const float* Wsl   = (const float*)d_in[7];
    const float* bsl   = (const float*)d_in[8];
    const float* tx    = (const float*)d_in[9];
    const float* phx   = (const float*)d_in[10];
    const float* Wfe   = (const float*)d_in[11];
    const float* bfe   = (const float*)d_in[12];
    const float* te    = (const float*)d_in[13];
    const float* Wes   = (const float*)d_in[14];
    const float* bes   = (const float*)d_in[15];
    const float* phe   = (const float*)d_in[16];

    float* out0 = (float*)d_out;                  // slice_token [B,M,C]
    float* out1 = out0 + (size_t)BB * MM * CC;    // slice_weight [B,N,M]
    float* ws   = (float*)d_ws;
    unsigned short* sw2b = (unsigned short*)(ws + WS_SW2);

    int PB = 64;
    while (PB > 8) {
        size_t need = (size_t)(WS_SPART + (size_t)BB * PB * MM * CC) * sizeof(float);
        if (need <= ws_size) break;
        PB >>= 1;
    }
    int rowsPB = NN / PB;
    int nb2 = BB * PB * 2;

    kPP<<<257, 256, 0, stream>>>(Wx, Wsl, bx, phx, bsl, tx, te, Wes, ws);
    kN1<<<512, 256, 0, stream>>>(x, ws, out1, sw2b, ws + WS_NORM);
    kEN2<<<nb2 + EE * BB / 256, 256, 0, stream>>>(x, out1, ws + WS_SPART, PB, rowsPB, nb2,
                                                  eattr, eidx, sw2b, bes,
                                                  ws + WS_T1, ws + WS_ESN);
    kR <<<1024, 256, 0, stream>>>(ws + WS_SPART, ws + WS_SSUM, PB);
    kF2<<<256, 256, 0, stream>>>(ws, Wfx, bfx, Wfe, bfe, phe, out0);
}

// Round 20
// 98.012 us; speedup vs baseline: 1.5971x; 1.0619x over previous
//
#include <hip/hip_runtime.h>

#define BB 4
#define NN 16384
#define EE 65536
#define CC 256
#define MM 64

// ws float offsets
#define WS_NORM   0                  // B*M (atomics, zeroed by kPP block 256)
#define WS_T1     256
#define WS_ESN    512
#define WS_BCOMB  768                // 64
#define WS_ITX    832                // 64
#define WS_ITE    896                // 64
#define WS_WES2   1024               // 64*64 fp32 (unused by kN1 now; kept)
#define WS_WCOMB  5120               // W_comb^T bf16 [64][256] = 16384 u16 = 8192 floats
#define WS_WES2T  13312              // Wes2^T bf16 [m=64][k=64] = 4096 u16 = 2048 floats
#define WS_SW2    21504              // bf16 SW2 [B*N*M ushorts] (8MB)
#define WS_SSUM   WS_SW2             // after kEN2, overlaid by Ssum [B*M*C floats]
#define WS_SPART  4215808            // B*PB*M*C partials

typedef __attribute__((ext_vector_type(8))) __bf16 bf16x8_t;
typedef __attribute__((ext_vector_type(4))) float f32x4_t;

static __device__ __forceinline__ unsigned short f2bf(float f) {
    unsigned int u = __float_as_uint(f);
    unsigned int r = (u + 0x7FFFu + ((u >> 16) & 1u)) >> 16;   // RNE
    return (unsigned short)r;
}

// ---------- PP: merged preamble + accumulator zeroing ----------
__global__ __launch_bounds__(256) void kPP(const float* __restrict__ Wx,
                                           const float* __restrict__ Wsl,
                                           const float* __restrict__ bx,
                                           const float* __restrict__ phx,
                                           const float* __restrict__ bsl,
                                           const float* __restrict__ tx,
                                           const float* __restrict__ te,
                                           const float* __restrict__ Wes,
                                           float* __restrict__ ws) {
    __shared__ float row[256];
    __shared__ float part[4][64];
    const int tid = threadIdx.x;
    const int m = tid & 63, kq = tid >> 6;
    if (blockIdx.x < 256) {
        const int c = blockIdx.x;
        row[tid] = Wx[c * CC + tid];
        __syncthreads();
        float acc = 0.f;
#pragma unroll 8
        for (int kk = 0; kk < 64; ++kk) {
            int k = kq * 64 + kk;
            acc += row[k] * Wsl[k * MM + m];
        }
        part[kq][m] = acc;
        __syncthreads();
        if (tid < 64) {
            float v = part[0][tid] + part[1][tid] + part[2][tid] + part[3][tid];
            ((unsigned short*)(ws + WS_WCOMB))[tid * 256 + c] = f2bf(v);
        }
    } else {
#pragma unroll
        for (int i = 0; i < 3; ++i) ws[i * 256 + tid] = 0.f;
        row[tid] = bx[tid] + phx[tid];
        __syncthreads();
        float acc = 0.f;
#pragma unroll 8
        for (int kk = 0; kk < 64; ++kk) {
            int k = kq * 64 + kk;
            acc += row[k] * Wsl[k * MM + m];
        }
        part[kq][m] = acc;
        __syncthreads();
        if (tid < 64) {
            ws[WS_BCOMB + tid] = bsl[tid] +
                part[0][tid] + part[1][tid] + part[2][tid] + part[3][tid];
            ws[WS_ITX + tid] = 1.f / fminf(fmaxf(tx[tid], 0.01f), 5.f);
            ws[WS_ITE + tid] = 1.f / fminf(fmaxf(te[tid], 0.01f), 5.f);
        }
        unsigned short* w2t = (unsigned short*)(ws + WS_WES2T);
#pragma unroll
        for (int i = 0; i < 16; ++i) {
            int e = i * 256 + tid;
            int m2 = e >> 6, k2 = e & 63;
            float itk = 1.f / fminf(fmaxf(te[k2], 0.01f), 5.f);
            w2t[m2 * 64 + k2] = f2bf(itk * Wes[k2 * 64 + m2]);
        }
    }
}

// ---------- N1: MFMA x@W_comb -> softmax -> sw + norm + MFMA sw@Wes2 -> sw2b ----------
// EXACT r19 form (proven).
__global__ __launch_bounds__(256, 2) void kN1(const float* __restrict__ x,
                                              const float* __restrict__ ws,
                                              float* __restrict__ out1,
                                              unsigned short* __restrict__ sw2b,
                                              float* __restrict__ norm_acc) {
    __shared__ float smem[17920];    // 71.7 KB
    __shared__ float redn[4][64];
    __shared__ float bcs[64], itxs[64];
    unsigned short* smem_u = (unsigned short*)smem;
    float* swl = smem + 4096;
    const int tid = threadIdx.x;
    const int wv = tid >> 6, l = tid & 63;
    const int ln = l & 15, kg = l >> 4;
    const int row0 = blockIdx.x * 128;
    const int b = blockIdx.x >> 7;
    const int r = tid >> 2;
    const int h = tid & 3;

    if (tid < 64) { bcs[tid] = ws[WS_BCOMB + tid]; itxs[tid] = ws[WS_ITX + tid]; }

    const unsigned short* wct = (const unsigned short*)(ws + WS_WCOMB);
#pragma unroll
    for (int i = 0; i < 8; ++i) {
        int f8 = (i * 256 + tid) * 8;
        int m = f8 >> 8, k = f8 & 255;
        *(uint4*)&smem_u[m * 264 + k] = *(const uint4*)&wct[f8];
    }
    __syncthreads();

    f32x4_t acc[2][4];
#pragma unroll
    for (int i = 0; i < 2; ++i)
#pragma unroll
        for (int j = 0; j < 4; ++j) acc[i][j] = (f32x4_t){0.f, 0.f, 0.f, 0.f};

    for (int c0 = 0; c0 < CC; c0 += 32) {
        bf16x8_t bf[4];
#pragma unroll
        for (int mt = 0; mt < 4; ++mt)
            bf[mt] = *(const bf16x8_t*)&smem_u[(mt * 16 + ln) * 264 + c0 + kg * 8];
#pragma unroll
        for (int rt = 0; rt < 2; ++rt) {
            int arow = row0 + (wv * 2 + rt) * 16 + ln;
            const float* ap = x + (size_t)arow * CC + c0 + kg * 8;
            float4 p0 = *(const float4*)ap;
            float4 p1 = *(const float4*)(ap + 4);
            union { unsigned short u[8]; bf16x8_t v; } af;
            af.u[0] = f2bf(p0.x); af.u[1] = f2bf(p0.y);
            af.u[2] = f2bf(p0.z); af.u[3] = f2bf(p0.w);
            af.u[4] = f2bf(p1.x); af.u[5] = f2bf(p1.y);
            af.u[6] = f2bf(p1.z); af.u[7] = f2bf(p1.w);
#pragma unroll
            for (int mt = 0; mt < 4; ++mt)
                acc[rt][mt] = __builtin_amdgcn_mfma_f32_16x16x32_bf16(
                    af.v, bf[mt], acc[rt][mt], 0, 0, 0);
        }
    }
    __syncthreads();

#pragma unroll
    for (int rt = 0; rt < 2; ++rt)
#pragma unroll
        for (int mt = 0; mt < 4; ++mt)
#pragma unroll
            for (int j = 0; j < 4; ++j)
                swl[((wv * 2 + rt) * 16 + kg * 4 + j) * 68 + mt * 16 + ln] =
                    acc[rt][mt][j];
    {
        const unsigned short* w2tg = (const unsigned short*)(ws + WS_WES2T);
        int m2 = tid >> 2, k2 = (tid & 3) * 16;
        *(uint4*)&smem_u[m2 * 80 + k2] = *(const uint4*)&w2tg[m2 * 64 + k2];
        *(uint4*)&smem_u[m2 * 80 + k2 + 8] = *(const uint4*)&w2tg[m2 * 64 + k2 + 8];
    }
    __syncthreads();

    float sacc[2][16];
#pragma unroll
    for (int i = 0; i < 2; ++i)
#pragma unroll
        for (int q = 0; q < 4; ++q) {
            float4 v = *(float4*)&swl[(r + 64 * i) * 68 + h * 16 + q * 4];
            sacc[i][q * 4 + 0] = v.x; sacc[i][q * 4 + 1] = v.y;
            sacc[i][q * 4 + 2] = v.z; sacc[i][q * 4 + 3] = v.w;
        }
    float colsum[16];
#pragma unroll
    for (int j = 0; j < 16; ++j) colsum[j] = 0.f;
#pragma unroll
    for (int i = 0; i < 2; ++i) {
        float mx = -1e30f;
#pragma unroll
        for (int j = 0; j < 16; ++j) {
            int m = h * 16 + j;
            sacc[i][j] = (sacc[i][j] + bcs[m]) * itxs[m];
            mx = fmaxf(mx, sacc[i][j]);
        }
        mx = fmaxf(mx, __shfl_xor(mx, 1));
        mx = fmaxf(mx, __shfl_xor(mx, 2));
        float s = 0.f;
#pragma unroll
        for (int j = 0; j < 16; ++j) { sacc[i][j] = __expf(sacc[i][j] - mx); s += sacc[i][j]; }
        s += __shfl_xor(s, 1);
        s += __shfl_xor(s, 2);
        float inv = 1.f / s;
        int rl = r + 64 * i;
        int row = row0 + rl;
#pragma unroll
        for (int q = 0; q < 4; ++q) {
            float4 v = {sacc[i][q * 4 + 0] * inv, sacc[i][q * 4 + 1] * inv,
                        sacc[i][q * 4 + 2] * inv, sacc[i][q * 4 + 3] * inv};
            *(float4*)(out1 + (size_t)row * MM + h * 16 + q * 4) = v;
            *(float4*)&swl[rl * 68 + h * 16 + q * 4] = v;
#pragma unroll
            for (int j = 0; j < 4; ++j) colsum[q * 4 + j] += ((float*)&v)[j];
        }
    }
#pragma unroll
    for (int j = 0; j < 16; ++j) {
        colsum[j] += __shfl_xor(colsum[j], 4);
        colsum[j] += __shfl_xor(colsum[j], 8);
        colsum[j] += __shfl_xor(colsum[j], 16);
        colsum[j] += __shfl_xor(colsum[j], 32);
    }
    if (l < 4) {
#pragma unroll
        for (int j = 0; j < 16; ++j) redn[wv][h * 16 + j] = colsum[j];
    }
    __syncthreads();

    f32x4_t eacc[2][4];
#pragma unroll
    for (int i = 0; i < 2; ++i)
#pragma unroll
        for (int j = 0; j < 4; ++j) eacc[i][j] = (f32x4_t){0.f, 0.f, 0.f, 0.f};
#pragma unroll
    for (int ks = 0; ks < 2; ++ks) {
        bf16x8_t bfw[4];
#pragma unroll
        for (int mt = 0; mt < 4; ++mt)
            bfw[mt] = *(const bf16x8_t*)&smem_u[(mt * 16 + ln) * 80 + ks * 32 + kg * 8];
#pragma unroll
        for (int rt = 0; rt < 2; ++rt) {
            const float* ap = &swl[((wv * 2 + rt) * 16 + ln) * 68 + ks * 32 + kg * 8];
            float4 p0 = *(const float4*)ap;
            float4 p1 = *(const float4*)(ap + 4);
            union { unsigned short u[8]; bf16x8_t v; } af;
            af.u[0] = f2bf(p0.x); af.u[1] = f2bf(p0.y);
            af.u[2] = f2bf(p0.z); af.u[3] = f2bf(p0.w);
            af.u[4] = f2bf(p1.x); af.u[5] = f2bf(p1.y);
            af.u[6] = f2bf(p1.z); af.u[7] = f2bf(p1.w);
#pragma unroll
            for (int mt = 0; mt < 4; ++mt)
                eacc[rt][mt] = __builtin_amdgcn_mfma_f32_16x16x32_bf16(
                    af.v, bfw[mt], eacc[rt][mt], 0, 0, 0);
        }
    }
    {
        unsigned short* esb = (unsigned short*)(smem + 12800);
#pragma unroll
        for (int rt = 0; rt < 2; ++rt)
#pragma unroll
            for (int mt = 0; mt < 4; ++mt)
#pragma unroll
                for (int j = 0; j < 4; ++j)
                    esb[((wv * 2 + rt) * 16 + kg * 4 + j) * 80 + mt * 16 + ln] =
                        f2bf(eacc[rt][mt][j]);
    }
    __syncthreads();
    {
        const unsigned short* esb = (const unsigned short*)(smem + 12800);
        int row = tid >> 1, half = tid & 1;
        const uint4* src = (const uint4*)&esb[row * 80 + half * 32];
        uint4* dst = (uint4*)(sw2b + (size_t)(row0 + row) * MM + half * 32);
        dst[0] = src[0]; dst[1] = src[1]; dst[2] = src[2]; dst[3] = src[3];
    }

    if (tid < 64)
        atomicAdd(&norm_acc[b * MM + tid],
                  redn[0][tid] + redn[1][tid] + redn[2][tid] + redn[3][tid]);
}

// ---------- EN2: grid-fused MFMA-kN2 (blocks 0..nb2-1) + kE (blocks nb2..) ----------
// r20: kN2 half rewritten as bf16 MFMA (Spart = sw^T @ x). LDS-transposed
// staging xT[c][r], swT[m][r] (stride 40 u16, 16B rows) with 2-bit XOR chunk
// swizzle ((r>>3)^((row>>2)&3)) -> write conflicts ~4-way, frag reads ~2-way.
// Operand order mirrors kN1's verified mapping: A=swT (D-rows=m), B=xT (D-cols=c).
// Error via /norm ~1e-3 on out0 — safe (threshold 2e-2).
__global__ __launch_bounds__(256, 4) void kEN2(const float* __restrict__ x,
                                               const float* __restrict__ sw,
                                               float* __restrict__ Spart,
                                               int PB, int rowsPB, int nb2,
                                               const float* __restrict__ eattr,
                                               const int* __restrict__ eidx,
                                               const unsigned short* __restrict__ sw2b,
                                               const float* __restrict__ bes,
                                               float* __restrict__ t1_acc,
                                               float* __restrict__ esn_acc) {
    __shared__ float smem[9280];   // 37.1 KB union
    const int tid = threadIdx.x;
    if ((int)blockIdx.x < nb2) {
        // xT u16 [128][40] at bytes 0..10239; sT u16 [64][40] at bytes 10240..15359
        unsigned short* xT = (unsigned short*)smem;
        unsigned short* sT = (unsigned short*)(smem + 2560);
        const int bid = blockIdx.x;
        const int ch = bid & 1;
        const int p = (bid >> 1) % PB, b = (bid >> 1) / PB;
        const int base = b * NN + p * rowsPB;
        const int wv = tid >> 6, l = tid & 63;
        const int ln = l & 15, kg = l >> 4;
        const int ct0 = wv * 2;

        f32x4_t acc[2][4];   // [ct][mt]
#pragma unroll
        for (int i = 0; i < 2; ++i)
#pragma unroll
            for (int j = 0; j < 4; ++j) acc[i][j] = (f32x4_t){0.f, 0.f, 0.f, 0.f};

        for (int r0 = 0; r0 < rowsPB; r0 += 32) {
            __syncthreads();
            // stage x half (32 r x 128 c) transposed bf16
#pragma unroll
            for (int i = 0; i < 4; ++i) {
                int flat = i * 256 + tid;
                int rr = flat >> 5, c = (flat & 31) * 4;
                float4 v = *(const float4*)(x + (size_t)(base + r0 + rr) * CC + ch * 128 + c);
                int key = (c >> 2) & 3;
                int off = ((rr >> 3) ^ key) * 8 + (rr & 7);
                xT[(c + 0) * 40 + off] = f2bf(v.x);
                xT[(c + 1) * 40 + off] = f2bf(v.y);
                xT[(c + 2) * 40 + off] = f2bf(v.z);
                xT[(c + 3) * 40 + off] = f2bf(v.w);
            }
            // stage sw (32 r x 64 m) transposed bf16
#pragma unroll
            for (int i = 0; i < 2; ++i) {
                int flat = i * 256 + tid;
                int rr = flat >> 4, m = (flat & 15) * 4;
                float4 v = *(const float4*)(sw + (size_t)(base + r0 + rr) * MM + m);
                int key = (m >> 2) & 3;
                int off = ((rr >> 3) ^ key) * 8 + (rr & 7);
                sT[(m + 0) * 40 + off] = f2bf(v.x);
                sT[(m + 1) * 40 + off] = f2bf(v.y);
                sT[(m + 2) * 40 + off] = f2bf(v.z);
                sT[(m + 3) * 40 + off] = f2bf(v.w);
            }
            __syncthreads();
            bf16x8_t afr[4];
#pragma unroll
            for (int mt = 0; mt < 4; ++mt) {
                int m = mt * 16 + ln;
                int chunk = kg ^ ((m >> 2) & 3);
                afr[mt] = *(const bf16x8_t*)&sT[m * 40 + chunk * 8];
            }
#pragma unroll
            for (int ct = 0; ct < 2; ++ct) {
                int c = (ct0 + ct) * 16 + ln;
                int chunk = kg ^ ((c >> 2) & 3);
                bf16x8_t bfr = *(const bf16x8_t*)&xT[c * 40 + chunk * 8];
#pragma unroll
                for (int mt = 0; mt < 4; ++mt)
                    acc[ct][mt] = __builtin_amdgcn_mfma_f32_16x16x32_bf16(
                        afr[mt], bfr, acc[ct][mt], 0, 0, 0);
            }
        }
        float* dst = Spart + (size_t)(b * PB + p) * MM * CC + ch * 128;
#pragma unroll
        for (int ct = 0; ct < 2; ++ct)
#pragma unroll
            for (int mt = 0; mt < 4; ++mt)
#pragma unroll
                for (int j = 0; j < 4; ++j) {
                    int m = mt * 16 + kg * 4 + j;
                    int c = (ct0 + ct) * 16 + ln;
                    dst[(size_t)m * CC + c] = acc[ct][mt][j];
                }
    } else {
        float* u    = smem;
        float* eav  = smem + 8448;
        float* redt = smem + 8704;
        float* redn = smem + 8960;
        float* bes_s = smem + 9216;
        const int w = tid >> 6, l = tid & 63;
        const int eg = ((int)blockIdx.x - nb2) * 256 + tid;
        const int b = eg >> 16;
        if (tid < 64) bes_s[tid] = bes[tid];
        const int2 idx = ((const int2*)eidx)[eg];
        const float ea = eattr[eg];
        const uint4* g0 = (const uint4*)(sw2b + (size_t)(b * NN + idx.x) * MM);
        const uint4* g1 = (const uint4*)(sw2b + (size_t)(b * NN + idx.y) * MM);
        eav[w * 64 + l] = ea;
        __syncthreads();

        float v[64];
#pragma unroll
        for (int q = 0; q < 8; ++q) {
            uint4 a = g0[q], c = g1[q];
            unsigned int au[4] = {a.x, a.y, a.z, a.w};
            unsigned int cu[4] = {c.x, c.y, c.z, c.w};
#pragma unroll
            for (int j = 0; j < 4; ++j) {
                int m = q * 8 + j * 2;
                v[m + 0] = __uint_as_float(au[j] << 16) + __uint_as_float(cu[j] << 16) + bes_s[m + 0];
                v[m + 1] = __uint_as_float(au[j] & 0xFFFF0000u) + __uint_as_float(cu[j] & 0xFFFF0000u) + bes_s[m + 1];
            }
        }
        float mx = -1e30f;
#pragma unroll
        for (int m = 0; m < 64; ++m) mx = fmaxf(mx, v[m]);
        float s = 0.f;
#pragma unroll
        for (int m = 0; m < 64; ++m) { v[m] = __expf(v[m] - mx); s += v[m]; }
        float inv = 1.f / s;

        const int ml = l & 31, rh = l >> 5;
#pragma unroll
        for (int ph = 0; ph < 2; ++ph) {
            __syncthreads();
#pragma unroll
            for (int j = 0; j < 32; ++j) u[w * 2112 + l * 33 + j] = v[ph * 32 + j] * inv;
            __syncthreads();
            float t = 0.f, n = 0.f;
#pragma unroll 8
            for (int rr = 0; rr < 32; ++rr) {
                int r = rh * 32 + rr;
                float e = u[w * 2112 + r * 33 + ml];
                n += e;
                t += e * eav[w * 64 + r];
            }
            t += __shfl_xor(t, 32);
            n += __shfl_xor(n, 32);
            if (l < 32) { redt[w * 64 + ph * 32 + l] = t; redn[w * 64 + ph * 32 + l] = n; }
        }
        __syncthreads();
        if (tid < 64) {
            atomicAdd(&t1_acc[b * 64 + tid],
                      redt[tid] + redt[64 + tid] + redt[128 + tid] + redt[192 + tid]);
            atomicAdd(&esn_acc[b * 64 + tid],
                      redn[tid] + redn[64 + tid] + redn[128 + tid] + redn[192 + tid]);
        }
    }
}

// ---------- R: parallel partial reduce Spart -> Ssum [B,M,C] ----------
__global__ __launch_bounds__(256) void kR(const float* __restrict__ Spart,
                                          float* __restrict__ Ssum, int PB) {
    const int idx = blockIdx.x * 256 + threadIdx.x;
    const int b = idx >> 14;
    const int mc = idx & 16383;
    const float* sp = Spart + (size_t)b * PB * MM * CC + mc;
    float a0 = 0.f, a1 = 0.f, a2 = 0.f, a3 = 0.f;
    for (int p = 0; p < PB; p += 4) {
        a0 += sp[(size_t)(p + 0) * MM * CC];
        a1 += sp[(size_t)(p + 1) * MM * CC];
        a2 += sp[(size_t)(p + 2) * MM * CC];
        a3 += sp[(size_t)(p + 3) * MM * CC];
    }
    Ssum[idx] = (a0 + a1) + (a2 + a3);
}

// ---------- F2: matvec + combine -> slice_token ----------
__global__ __launch_bounds__(256) void kF2(const float* __restrict__ ws,
                                           const float* __restrict__ Wfx,
                                           const float* __restrict__ bfx,
                                           const float* __restrict__ Wfe,
                                           const float* __restrict__ bfe,
                                           const float* __restrict__ phe,
                                           float* __restrict__ out0) {
    __shared__ float srow[256];
    const int bid = blockIdx.x;
    const int b = bid >> 6, m = bid & 63;
    const int t = threadIdx.x;
    srow[t] = ws[WS_SSUM + (size_t)(b * MM + m) * CC + t];
    __syncthreads();
    float acc = 0.f;
#pragma unroll 8
    for (int k = 0; k < 256; ++k) acc += srow[k] * Wfx[k * CC + t];
    float nv  = ws[WS_NORM + b * 64 + m];
    float t1v = ws[WS_T1   + b * 64 + m];
    float ev  = ws[WS_ESN  + b * 64 + m];
    const float scale = (float)NN / (float)EE;   // 0.25
    float num = acc + nv * bfx[t] + scale * (t1v * Wfe[t] + ev * (bfe[t] + phe[t]));
    float den = nv + scale * ev + 1e-5f;
    out0[(size_t)(b * MM + m) * CC + t] = num / den;
}

extern "C" void kernel_launch(void* const* d_in, const int* in_sizes, int n_in,
                              void* d_out, int out_size, void* d_ws, size_t ws_size,
                              hipStream_t stream) {
    const float* x     = (const float*)d_in[0];
    const float* eattr = (const float*)d_in[1];
    const int*   eidx  = (const int*)d_in[2];
    const float* Wfx   = (const float*)d_in[3];
    const float* bfx   = (const float*)d_in[4];
    const float* Wx    = (const float*)d_in[5];
    const float* bx    = (const float*)d_in[6];
    const float* Wsl   = (const float*)d_in[7];
    const float* bsl   = (const float*)d_in[8];
    const float* tx    = (const float*)d_in[9];
    const float* phx   = (const float*)d_in[10];
    const float* Wfe   = (const float*)d_in[11];
    const float* bfe   = (const float*)d_in[12];
    const float* te    = (const float*)d_in[13];
    const float* Wes   = (const float*)d_in[14];
    const float* bes   = (const float*)d_in[15];
    const float* phe   = (const float*)d_in[16];

    float* out0 = (float*)d_out;                  // slice_token [B,M,C]
    float* out1 = out0 + (size_t)BB * MM * CC;    // slice_weight [B,N,M]
    float* ws   = (float*)d_ws;
    unsigned short* sw2b = (unsigned short*)(ws + WS_SW2);

    int PB = 64;
    while (PB > 8) {
        size_t need = (size_t)(WS_SPART + (size_t)BB * PB * MM * CC) * sizeof(float);
        if (need <= ws_size) break;
        PB >>= 1;
    }
    int rowsPB = NN / PB;
    int nb2 = BB * PB * 2;

    kPP<<<257, 256, 0, stream>>>(Wx, Wsl, bx, phx, bsl, tx, te, Wes, ws);
    kN1<<<512, 256, 0, stream>>>(x, ws, out1, sw2b, ws + WS_NORM);
    kEN2<<<nb2 + EE * BB / 256, 256, 0, stream>>>(x, out1, ws + WS_SPART, PB, rowsPB, nb2,
                                                  eattr, eidx, sw2b, bes,
                                                  ws + WS_T1, ws + WS_ESN);
    kR <<<1024, 256, 0, stream>>>(ws + WS_SPART, ws + WS_SSUM, PB);
    kF2<<<256, 256, 0, stream>>>(ws, Wfx, bfx, Wfe, bfe, phe, out0);
}